// Round 1
// baseline (1872.609 us; speedup 1.0000x reference)
//
#include <hip/hip_runtime.h>
#include <math.h>

#define NN 8192      // nodes
#define NE 131072    // edges
#define ZK 288       // padded z width (258 -> 288, multiple of 32)
#define NG 64        // graphs

// ---------------------------------------------------------------- counts
__global__ __launch_bounds__(256) void k_counts(const int* __restrict__ ei,
    const int* __restrict__ batch, int* ncnt, int* ecnt, int* indeg)
{
    int tid = blockIdx.x * 256 + threadIdx.x;
    if (tid < NE) {
        int src = ei[tid], dst = ei[NE + tid];
        atomicAdd(&ecnt[batch[src]], 1);
        atomicAdd(&indeg[dst], 1);
    }
    if (tid < NN) atomicAdd(&ncnt[batch[tid]], 1);
}

// ------------------------------------------------- encoder + size feats -> z
__global__ __launch_bounds__(256) void k_encoder(const float* __restrict__ x,
    const float* __restrict__ encW, const float* __restrict__ encb,
    const int* __restrict__ batch, const int* __restrict__ ncnt,
    const int* __restrict__ ecnt, float* __restrict__ z)
{
    int n = blockIdx.x, c = threadIdx.x;
    __shared__ float xr[8];
    if (c < 6) xr[c] = x[n * 6 + c];
    __syncthreads();
    float a = encb[c];
#pragma unroll
    for (int i = 0; i < 6; ++i) a = fmaf(xr[i], encW[i * 256 + c], a);
    z[n * ZK + c] = fmaxf(a, 0.f);
    if (c == 0) {
        int g = batch[n];
        z[n * ZK + 256] = log1pf((float)ncnt[g]);
        z[n * ZK + 257] = log1pf((float)ecnt[g]);
    }
    if (c >= 2 && c < 32) z[n * ZK + 256 + c] = 0.f;  // zero pad 258..287
}

// ---------------------------------------------------------------- CSR build
__global__ __launch_bounds__(256) void k_scan(const int* __restrict__ indeg,
                                              int* __restrict__ rowptr)
{
    __shared__ int part[256];
    int t = threadIdx.x;
    int base = t * 32, s = 0;
    for (int i = 0; i < 32; ++i) s += indeg[base + i];
    part[t] = s;
    __syncthreads();
    if (t == 0) {
        int run = 0;
        for (int i = 0; i < 256; ++i) { int v = part[i]; part[i] = run; run += v; }
        rowptr[NN] = run;
    }
    __syncthreads();
    int run = part[t];
    for (int i = 0; i < 32; ++i) { rowptr[base + i] = run; run += indeg[base + i]; }
}

__global__ __launch_bounds__(256) void k_fill(const int* __restrict__ ei,
    const int* __restrict__ rowptr, int* __restrict__ cursor, int* __restrict__ colidx)
{
    int tid = blockIdx.x * 256 + threadIdx.x;
    if (tid >= NE) return;
    int dst = ei[NE + tid];
    int pos = atomicAdd(&cursor[dst], 1);
    colidx[rowptr[dst] + pos] = ei[tid];
}

// ------------------------------------------------------- weight preparation
__global__ __launch_bounds__(256) void k_prep_qk(const float* __restrict__ qW,
    const float* __restrict__ kW, float* __restrict__ Wq, float* __restrict__ Wk)
{
    int idx = blockIdx.x * 256 + threadIdx.x;  // < ZK*256 exactly
    int r = idx >> 8, c = idx & 255;
    Wq[idx] = (r < 258) ? qW[r * 256 + c] : 0.f;
    Wk[idx] = (r < 258) ? kW[r * 256 + c] : 0.f;
}

// W_vo = v_W @ out_W (padded to ZK rows), bvo = v_b @ out_W
__global__ __launch_bounds__(256) void k_prep_vo(const float* __restrict__ vW,
    const float* __restrict__ vb, const float* __restrict__ outW,
    float* __restrict__ Wvo, float* __restrict__ bvo)
{
    int idx = blockIdx.x * 256 + threadIdx.x;
    if (idx < ZK * 8) {
        int r = idx >> 3, e = idx & 7;
        float s = 0.f;
        if (r < 258)
            for (int c = 0; c < 256; ++c) s = fmaf(vW[r * 256 + c], outW[c * 8 + e], s);
        Wvo[idx] = s;
    } else if (idx < ZK * 8 + 8) {
        int e = idx - ZK * 8;
        float s = 0.f;
        for (int c = 0; c < 256; ++c) s = fmaf(vb[c], outW[c * 8 + e], s);
        bvo[e] = s;
    }
}

// ------------------------------------------------------------- fp32 GEMM
// C[M,N=64*gx] = act(A[M,K] @ B[K,N] + bias) ; BM=128 BN=64 BK=32, 256 thr,
// 8x4 microtile (two 4-row quads -> conflict-free LDS reads)
__global__ __launch_bounds__(256) void k_gemm(
    const float* __restrict__ A, const float* __restrict__ B,
    const float* __restrict__ bias, float* __restrict__ C,
    int K, int lda, int ldb, int ldc,
    long long bStrideZ, long long cStrideZ, int biasStrideZ, int relu)
{
    B    += (size_t)blockIdx.z * bStrideZ;
    C    += (size_t)blockIdx.z * cStrideZ;
    bias += (size_t)blockIdx.z * biasStrideZ;
    __shared__ float As[32][132];
    __shared__ float Bs[32][68];
    int t = threadIdx.x;
    int m0 = blockIdx.y * 128, n0 = blockIdx.x * 64;
    int tr = t & 15, tc = t >> 4;
    float acc[8][4];
#pragma unroll
    for (int i = 0; i < 8; ++i)
#pragma unroll
        for (int j = 0; j < 4; ++j) acc[i][j] = 0.f;

    for (int k0 = 0; k0 < K; k0 += 32) {
#pragma unroll
        for (int i = 0; i < 4; ++i) {
            int f = t + 256 * i;
            int kc = f & 7, row = f >> 3;
            float4 v = *(const float4*)&A[(size_t)(m0 + row) * lda + k0 + 4 * kc];
            As[4 * kc + 0][row] = v.x; As[4 * kc + 1][row] = v.y;
            As[4 * kc + 2][row] = v.z; As[4 * kc + 3][row] = v.w;
        }
#pragma unroll
        for (int i = 0; i < 2; ++i) {
            int f = t + 256 * i;
            int nc = f & 15, krow = f >> 4;
            *(float4*)&Bs[krow][4 * nc] =
                *(const float4*)&B[(size_t)(k0 + krow) * ldb + n0 + 4 * nc];
        }
        __syncthreads();
#pragma unroll
        for (int kk = 0; kk < 32; ++kk) {
            float4 a0 = *(const float4*)&As[kk][4 * tr];
            float4 a1 = *(const float4*)&As[kk][64 + 4 * tr];
            float4 b  = *(const float4*)&Bs[kk][4 * tc];
            const float av0[4] = {a0.x, a0.y, a0.z, a0.w};
            const float av1[4] = {a1.x, a1.y, a1.z, a1.w};
            const float bv[4]  = {b.x, b.y, b.z, b.w};
#pragma unroll
            for (int i = 0; i < 4; ++i)
#pragma unroll
                for (int j = 0; j < 4; ++j) {
                    acc[i][j]     = fmaf(av0[i], bv[j], acc[i][j]);
                    acc[4 + i][j] = fmaf(av1[i], bv[j], acc[4 + i][j]);
                }
        }
        __syncthreads();
    }
    float4 bi = *(const float4*)&bias[n0 + 4 * tc];
#pragma unroll
    for (int h = 0; h < 2; ++h)
#pragma unroll
        for (int i = 0; i < 4; ++i) {
            int m = m0 + h * 64 + 4 * tr + i;
            float4 o;
            o.x = acc[h * 4 + i][0] + bi.x;
            o.y = acc[h * 4 + i][1] + bi.y;
            o.z = acc[h * 4 + i][2] + bi.z;
            o.w = acc[h * 4 + i][3] + bi.w;
            if (relu) {
                o.x = fmaxf(o.x, 0.f); o.y = fmaxf(o.y, 0.f);
                o.z = fmaxf(o.z, 0.f); o.w = fmaxf(o.w, 0.f);
            }
            *(float4*)&C[(size_t)m * ldc + n0 + 4 * tc] = o;
        }
}

// ------------------------------------------------------------- vo = z @ Wvo
__global__ __launch_bounds__(256) void k_vo(const float* __restrict__ z,
    const float* __restrict__ Wvo, const float* __restrict__ bvo,
    float* __restrict__ vo)
{
    int n = blockIdx.x * 4 + (threadIdx.x >> 6);
    int lane = threadIdx.x & 63;
    float p[8];
#pragma unroll
    for (int e = 0; e < 8; ++e) p[e] = 0.f;
    for (int kk = lane; kk < ZK; kk += 64) {
        float zv = z[(size_t)n * ZK + kk];
        float4 w0 = *(const float4*)&Wvo[kk * 8];
        float4 w1 = *(const float4*)&Wvo[kk * 8 + 4];
        p[0] = fmaf(zv, w0.x, p[0]); p[1] = fmaf(zv, w0.y, p[1]);
        p[2] = fmaf(zv, w0.z, p[2]); p[3] = fmaf(zv, w0.w, p[3]);
        p[4] = fmaf(zv, w1.x, p[4]); p[5] = fmaf(zv, w1.y, p[5]);
        p[6] = fmaf(zv, w1.z, p[6]); p[7] = fmaf(zv, w1.w, p[7]);
    }
#pragma unroll
    for (int msk = 1; msk <= 32; msk <<= 1)
#pragma unroll
        for (int e = 0; e < 8; ++e) p[e] += __shfl_xor(p[e], msk);
    if (lane == 0) {
#pragma unroll
        for (int e = 0; e < 8; ++e) vo[n * 8 + e] = p[e] + bvo[e];
    }
}

// -------------------------------------- flash attention (fp32) with 8-col PV
// 32 q-rows per block, split-K=2, BK=256 per chunk. q^T in LDS, k from L1/L2.
__global__ __launch_bounds__(256) void k_attn(
    const float* __restrict__ q, const float* __restrict__ k,
    const float* __restrict__ vo, float* __restrict__ pm,
    float* __restrict__ pl, float* __restrict__ pacc, float scale)
{
    __shared__ float qt[256][36];
    __shared__ float wred[4][36];
    __shared__ float lred[4][36];
    __shared__ float pvred[4][32][8];
    __shared__ float mst[32], lst[32], accst[32][8];
    const int t = threadIdx.x;
    const int n0 = blockIdx.x * 32;
    const int split = blockIdx.y;
    for (int i = t; i < 32 * 256; i += 256) {
        int r = i >> 8, d = i & 255;
        qt[d][r] = q[(size_t)(n0 + r) * 256 + d] * scale;
    }
    if (t < 32) {
        mst[t] = -INFINITY; lst[t] = 0.f;
#pragma unroll
        for (int e = 0; e < 8; ++e) accst[t][e] = 0.f;
    }
    __syncthreads();
    const int tr = t & 7, tc = t >> 3;
    const int wv = t >> 6, lane = t & 63;

    for (int ch = 0; ch < 16; ++ch) {
        const int krbase = split * 4096 + ch * 256 + 8 * tc;
        const float* kp = k + (size_t)krbase * 256;
        float s[4][8];
#pragma unroll
        for (int i = 0; i < 4; ++i)
#pragma unroll
            for (int j = 0; j < 8; ++j) s[i][j] = 0.f;
#pragma unroll 2
        for (int d0 = 0; d0 < 256; d0 += 4) {
            float4 q0 = *(const float4*)&qt[d0 + 0][4 * tr];
            float4 q1 = *(const float4*)&qt[d0 + 1][4 * tr];
            float4 q2 = *(const float4*)&qt[d0 + 2][4 * tr];
            float4 q3 = *(const float4*)&qt[d0 + 3][4 * tr];
#pragma unroll
            for (int j = 0; j < 8; ++j) {
                float4 kv = *(const float4*)&kp[j * 256 + d0];
                s[0][j] = fmaf(q0.x, kv.x, s[0][j]); s[0][j] = fmaf(q1.x, kv.y, s[0][j]);
                s[0][j] = fmaf(q2.x, kv.z, s[0][j]); s[0][j] = fmaf(q3.x, kv.w, s[0][j]);
                s[1][j] = fmaf(q0.y, kv.x, s[1][j]); s[1][j] = fmaf(q1.y, kv.y, s[1][j]);
                s[1][j] = fmaf(q2.y, kv.z, s[1][j]); s[1][j] = fmaf(q3.y, kv.w, s[1][j]);
                s[2][j] = fmaf(q0.z, kv.x, s[2][j]); s[2][j] = fmaf(q1.z, kv.y, s[2][j]);
                s[2][j] = fmaf(q2.z, kv.z, s[2][j]); s[2][j] = fmaf(q3.z, kv.w, s[2][j]);
                s[3][j] = fmaf(q0.w, kv.x, s[3][j]); s[3][j] = fmaf(q1.w, kv.y, s[3][j]);
                s[3][j] = fmaf(q2.w, kv.z, s[3][j]); s[3][j] = fmaf(q3.w, kv.w, s[3][j]);
            }
        }
        // --- online softmax bookkeeping ---
        float tm[4];
#pragma unroll
        for (int i = 0; i < 4; ++i) {
            float a = fmaxf(fmaxf(s[i][0], s[i][1]), fmaxf(s[i][2], s[i][3]));
            float b = fmaxf(fmaxf(s[i][4], s[i][5]), fmaxf(s[i][6], s[i][7]));
            tm[i] = fmaxf(a, b);
        }
#pragma unroll
        for (int msk = 8; msk <= 32; msk <<= 1)
#pragma unroll
            for (int i = 0; i < 4; ++i) tm[i] = fmaxf(tm[i], __shfl_xor(tm[i], msk));
        if (lane < 8) {
#pragma unroll
            for (int i = 0; i < 4; ++i) wred[wv][4 * lane + i] = tm[i];
        }
        __syncthreads();
        float mnew[4];
#pragma unroll
        for (int i = 0; i < 4; ++i) {
            int r = 4 * tr + i;
            float tmax = fmaxf(fmaxf(wred[0][r], wred[1][r]), fmaxf(wred[2][r], wred[3][r]));
            mnew[i] = fmaxf(mst[r], tmax);
        }
        float ps[4] = {0.f, 0.f, 0.f, 0.f};
        float pv[4][8];
#pragma unroll
        for (int i = 0; i < 4; ++i)
#pragma unroll
            for (int e = 0; e < 8; ++e) pv[i][e] = 0.f;
#pragma unroll
        for (int j = 0; j < 8; ++j) {
            int kr = krbase + j;
            float4 va = *(const float4*)&vo[kr * 8];
            float4 vb4 = *(const float4*)&vo[kr * 8 + 4];
#pragma unroll
            for (int i = 0; i < 4; ++i) {
                float p = __expf(s[i][j] - mnew[i]);
                ps[i] += p;
                pv[i][0] = fmaf(p, va.x, pv[i][0]);  pv[i][1] = fmaf(p, va.y, pv[i][1]);
                pv[i][2] = fmaf(p, va.z, pv[i][2]);  pv[i][3] = fmaf(p, va.w, pv[i][3]);
                pv[i][4] = fmaf(p, vb4.x, pv[i][4]); pv[i][5] = fmaf(p, vb4.y, pv[i][5]);
                pv[i][6] = fmaf(p, vb4.z, pv[i][6]); pv[i][7] = fmaf(p, vb4.w, pv[i][7]);
            }
        }
#pragma unroll
        for (int msk = 8; msk <= 32; msk <<= 1) {
#pragma unroll
            for (int i = 0; i < 4; ++i) {
                ps[i] += __shfl_xor(ps[i], msk);
#pragma unroll
                for (int e = 0; e < 8; ++e) pv[i][e] += __shfl_xor(pv[i][e], msk);
            }
        }
        if (lane < 8) {
#pragma unroll
            for (int i = 0; i < 4; ++i) {
                lred[wv][4 * lane + i] = ps[i];
#pragma unroll
                for (int e = 0; e < 8; ++e) pvred[wv][4 * lane + i][e] = pv[i][e];
            }
        }
        __syncthreads();
        if (t < 32) {
            int r = t;
            float tmax = fmaxf(fmaxf(wred[0][r], wred[1][r]), fmaxf(wred[2][r], wred[3][r]));
            float mo = mst[r];
            float mn = fmaxf(mo, tmax);
            float rs = __expf(mo - mn);
            lst[r] = lst[r] * rs + (lred[0][r] + lred[1][r] + lred[2][r] + lred[3][r]);
            mst[r] = mn;
#pragma unroll
            for (int e = 0; e < 8; ++e)
                accst[r][e] = accst[r][e] * rs +
                    (pvred[0][r][e] + pvred[1][r][e] + pvred[2][r][e] + pvred[3][r][e]);
        }
        __syncthreads();
    }
    if (t < 32) {
        int n = n0 + t;
        pm[split * NN + n] = mst[t];
        pl[split * NN + n] = lst[t];
#pragma unroll
        for (int e = 0; e < 8; ++e) pacc[(size_t)split * NN * 8 + n * 8 + e] = accst[t][e];
    }
}

// ----------------------------------- merge split-K partials -> top2 weights
__global__ __launch_bounds__(256) void k_attn_merge(
    const float* __restrict__ pm, const float* __restrict__ pl,
    const float* __restrict__ pacc, const float* __restrict__ outb,
    float* __restrict__ sparse)
{
    int n = blockIdx.x * 256 + threadIdx.x;
    float m0 = pm[n], m1 = pm[NN + n];
    float mn = fmaxf(m0, m1);
    float r0 = __expf(m0 - mn), r1 = __expf(m1 - mn);
    float l = pl[n] * r0 + pl[NN + n] * r1;
    float inv = 1.f / l;
    float lg[8];
#pragma unroll
    for (int e = 0; e < 8; ++e)
        lg[e] = (pacc[n * 8 + e] * r0 + pacc[(size_t)NN * 8 + n * 8 + e] * r1) * inv + outb[e];
    int i1 = 0; float v1 = lg[0];
#pragma unroll
    for (int e = 1; e < 8; ++e) if (lg[e] > v1) { v1 = lg[e]; i1 = e; }
    int i2 = -1; float v2 = -INFINITY;
#pragma unroll
    for (int e = 0; e < 8; ++e) if (e != i1 && lg[e] > v2) { v2 = lg[e]; i2 = e; }
    float e2 = __expf(v2 - v1);
    float w1 = 1.f / (1.f + e2);
    float w2 = e2 / (1.f + e2);
#pragma unroll
    for (int e = 0; e < 8; ++e)
        sparse[n * 8 + e] = (e == i1) ? w1 : ((e == i2) ? w2 : 0.f);
}

// --------------------------- X = He + neigh_mean(He) (one wave per node)
__global__ __launch_bounds__(256) void k_agg(
    const float* __restrict__ src, int srcStride,
    const int* __restrict__ rowptr, const int* __restrict__ colidx,
    float* __restrict__ X)
{
    int n = blockIdx.x * 4 + (threadIdx.x >> 6);
    int c4 = (threadIdx.x & 63) * 4;
    int r0 = rowptr[n], r1 = rowptr[n + 1];
    float ax = 0.f, ay = 0.f, az = 0.f, aw = 0.f;
    for (int i = r0; i < r1; ++i) {
        int sn = colidx[i];
        float4 v = *(const float4*)&src[(size_t)sn * srcStride + c4];
        ax += v.x; ay += v.y; az += v.z; aw += v.w;
    }
    int deg = r1 - r0;
    float inv = 1.f / (float)(deg > 1 ? deg : 1);
    float4 self = *(const float4*)&src[(size_t)n * srcStride + c4];
    float4 o;
    o.x = self.x + ax * inv; o.y = self.y + ay * inv;
    o.z = self.z + az * inv; o.w = self.w + aw * inv;
    *(float4*)&X[(size_t)n * 256 + c4] = o;
}

// ---------------------------------------------------- top-2 weighted combine
__global__ __launch_bounds__(256) void k_combine(
    const float* __restrict__ He, const float* __restrict__ sparse,
    float* __restrict__ out)
{
    int n = blockIdx.x, o = threadIdx.x;
    float s = 0.f;
#pragma unroll
    for (int e = 0; e < 8; ++e) {
        float w = sparse[n * 8 + e];
        if (w != 0.f) s = fmaf(w, He[(size_t)e * NN * 256 + (size_t)n * 256 + o], s);
    }
    out[(size_t)n * 256 + o] = s;
}

// ==========================================================================
extern "C" void kernel_launch(void* const* d_in, const int* in_sizes, int n_in,
                              void* d_out, int out_size, void* d_ws, size_t ws_size,
                              hipStream_t stream)
{
    (void)n_in; (void)out_size;
    const float* x     = (const float*)d_in[0];
    const int*   ei    = (const int*)d_in[1];
    const int*   batch = (const int*)d_in[2];
    const float* encW  = (const float*)d_in[3];
    const float* encb  = (const float*)d_in[4];
    const float* qW    = (const float*)d_in[5];
    const float* qb    = (const float*)d_in[6];
    const float* kW    = (const float*)d_in[7];
    const float* kb    = (const float*)d_in[8];
    const float* vW    = (const float*)d_in[9];
    const float* vb    = (const float*)d_in[10];
    const float* outW  = (const float*)d_in[11];
    const float* outb  = (const float*)d_in[12];
    const float* eWh   = (const float*)d_in[13];
    const float* ebh   = (const float*)d_in[14];
    const float* eWo   = (const float*)d_in[15];
    const float* ebo   = (const float*)d_in[16];
    float* out = (float*)d_out;
    if (in_sizes[0] != NN * 6 || in_sizes[1] != 2 * NE) return;

    char* wsp = (char*)d_ws;
    size_t off = 0;
    auto alloc = [&](size_t bytes) -> void* {
        void* p = wsp + off;
        off += (bytes + 511) & ~(size_t)511;
        return p;
    };
    float* z      = (float*)alloc((size_t)NN * ZK * 4);
    float* qbuf   = (float*)alloc((size_t)NN * 256 * 4);
    float* kbuf   = (float*)alloc((size_t)NN * 256 * 4);
    float* vo     = (float*)alloc((size_t)NN * 8 * 4);
    float* sparse = (float*)alloc((size_t)NN * 8 * 4);
    float* X0     = (float*)alloc((size_t)NN * 256 * 4);
    float* He     = (float*)alloc((size_t)8 * NN * 256 * 4);
    float* Wq     = (float*)alloc((size_t)ZK * 256 * 4);
    float* Wk     = (float*)alloc((size_t)ZK * 256 * 4);
    float* Wvo    = (float*)alloc((size_t)ZK * 8 * 4);
    float* bvo    = (float*)alloc(8 * 4);
    float* pm     = (float*)alloc((size_t)2 * NN * 4);
    float* pl     = (float*)alloc((size_t)2 * NN * 4);
    float* pacc   = (float*)alloc((size_t)2 * NN * 8 * 4);
    int* ints     = (int*)alloc((size_t)(NG + NG + NN + NN) * 4);
    int* ncnt = ints, *ecnt = ints + NG, *indeg = ecnt + NG, *cursor = indeg + NN;
    int* rowptr   = (int*)alloc((size_t)(NN + 1) * 4);
    int* colidx   = (int*)alloc((size_t)NE * 4);
    if (off > ws_size) return;  // workspace too small -> fail visibly

    hipMemsetAsync(ints, 0, (size_t)(NG + NG + NN + NN) * 4, stream);
    k_counts<<<(NE + 255) / 256, 256, 0, stream>>>(ei, batch, ncnt, ecnt, indeg);
    k_prep_qk<<<ZK, 256, 0, stream>>>(qW, kW, Wq, Wk);
    k_prep_vo<<<(ZK * 8 + 8 + 255) / 256, 256, 0, stream>>>(vW, vb, outW, Wvo, bvo);
    k_encoder<<<NN, 256, 0, stream>>>(x, encW, encb, batch, ncnt, ecnt, z);
    k_scan<<<1, 256, 0, stream>>>(indeg, rowptr);
    k_fill<<<(NE + 255) / 256, 256, 0, stream>>>(ei, rowptr, cursor, colidx);

    dim3 g1(256 / 64, NN / 128, 1);
    k_gemm<<<g1, 256, 0, stream>>>(z, Wq, qb, qbuf, ZK, ZK, 256, 256, 0, 0, 0, 0);
    k_gemm<<<g1, 256, 0, stream>>>(z, Wk, kb, kbuf, ZK, ZK, 256, 256, 0, 0, 0, 0);
    k_vo<<<NN / 4, 256, 0, stream>>>(z, Wvo, bvo, vo);

    float scale = 1.f / sqrtf(258.f);
    dim3 ga(NN / 32, 2, 1);
    k_attn<<<ga, 256, 0, stream>>>(qbuf, kbuf, vo, pm, pl, pacc, scale);
    k_attn_merge<<<NN / 256, 256, 0, stream>>>(pm, pl, pacc, outb, sparse);

    // experts
    k_agg<<<NN / 4, 256, 0, stream>>>(z, ZK, rowptr, colidx, X0);
    dim3 g8(256 / 64, NN / 128, 8);
    k_gemm<<<g8, 256, 0, stream>>>(X0, eWh, ebh, He, 256, 256, 256, 256,
                                   (long long)2 * 65536, (long long)NN * 256, 2 * 256, 1);
    for (int e = 0; e < 8; ++e) {
        k_agg<<<NN / 4, 256, 0, stream>>>(He + (size_t)e * NN * 256, 256, rowptr, colidx, X0);
        k_gemm<<<g1, 256, 0, stream>>>(X0, eWh + (size_t)(e * 2 + 1) * 65536,
                                       ebh + (e * 2 + 1) * 256, He + (size_t)e * NN * 256,
                                       256, 256, 256, 256, 0, 0, 0, 1);
    }
    for (int e = 0; e < 8; ++e) {
        k_agg<<<NN / 4, 256, 0, stream>>>(He + (size_t)e * NN * 256, 256, rowptr, colidx, X0);
        k_gemm<<<g1, 256, 0, stream>>>(X0, eWo + (size_t)e * 65536, ebo + e * 256,
                                       He + (size_t)e * NN * 256,
                                       256, 256, 256, 256, 0, 0, 0, 0);
    }
    k_combine<<<NN, 256, 0, stream>>>(He, sparse, out);
}

// Round 2
// 1484.321 us; speedup vs baseline: 1.2616x; 1.2616x over previous
//
#include <hip/hip_runtime.h>
#include <math.h>

#define NN 8192      // nodes
#define NE 131072    // edges
#define ZK 288       // padded z width (258 -> 288, multiple of 32)
#define NG 64        // graphs
#define NSPLIT 3     // attention split-K factor (768 blocks = 3/CU)

typedef __attribute__((ext_vector_type(8))) short bf16x8;
typedef __attribute__((ext_vector_type(4))) float f32x4;

static __device__ __forceinline__ unsigned short f2bf(float f) {
    unsigned u = __float_as_uint(f);
    unsigned r = (u + 0x7FFFu + ((u >> 16) & 1u)) >> 16;   // RNE
    return (unsigned short)r;
}
static __device__ __forceinline__ float b2f(unsigned short h) {
    return __uint_as_float(((unsigned)h) << 16);
}

// ---------------------------------------------------------------- counts
__global__ __launch_bounds__(256) void k_counts(const int* __restrict__ ei,
    const int* __restrict__ batch, int* ncnt, int* ecnt, int* indeg)
{
    int tid = blockIdx.x * 256 + threadIdx.x;
    if (tid < NE) {
        int src = ei[tid], dst = ei[NE + tid];
        atomicAdd(&ecnt[batch[src]], 1);
        atomicAdd(&indeg[dst], 1);
    }
    if (tid < NN) atomicAdd(&ncnt[batch[tid]], 1);
}

// ------------------------------------------------- encoder + size feats -> z
__global__ __launch_bounds__(256) void k_encoder(const float* __restrict__ x,
    const float* __restrict__ encW, const float* __restrict__ encb,
    const int* __restrict__ batch, const int* __restrict__ ncnt,
    const int* __restrict__ ecnt, float* __restrict__ z)
{
    int n = blockIdx.x, c = threadIdx.x;
    __shared__ float xr[8];
    if (c < 6) xr[c] = x[n * 6 + c];
    __syncthreads();
    float a = encb[c];
#pragma unroll
    for (int i = 0; i < 6; ++i) a = fmaf(xr[i], encW[i * 256 + c], a);
    z[n * ZK + c] = fmaxf(a, 0.f);
    if (c == 0) {
        int g = batch[n];
        z[n * ZK + 256] = log1pf((float)ncnt[g]);
        z[n * ZK + 257] = log1pf((float)ecnt[g]);
    }
    if (c >= 2 && c < 32) z[n * ZK + 256 + c] = 0.f;  // zero pad 258..287
}

// ---------------------------------------------------------------- CSR build
__global__ __launch_bounds__(256) void k_scan(const int* __restrict__ indeg,
                                              int* __restrict__ rowptr)
{
    __shared__ int part[256];
    int t = threadIdx.x;
    int base = t * 32, s = 0;
    for (int i = 0; i < 32; ++i) s += indeg[base + i];
    part[t] = s;
    __syncthreads();
    if (t == 0) {
        int run = 0;
        for (int i = 0; i < 256; ++i) { int v = part[i]; part[i] = run; run += v; }
        rowptr[NN] = run;
    }
    __syncthreads();
    int run = part[t];
    for (int i = 0; i < 32; ++i) { rowptr[base + i] = run; run += indeg[base + i]; }
}

__global__ __launch_bounds__(256) void k_fill(const int* __restrict__ ei,
    const int* __restrict__ rowptr, int* __restrict__ cursor, int* __restrict__ colidx)
{
    int tid = blockIdx.x * 256 + threadIdx.x;
    if (tid >= NE) return;
    int dst = ei[NE + tid];
    int pos = atomicAdd(&cursor[dst], 1);
    colidx[rowptr[dst] + pos] = ei[tid];
}

// ------------------------------------------------------- weight preparation
__global__ __launch_bounds__(256) void k_prep_qk(const float* __restrict__ qW,
    const float* __restrict__ kW, float* __restrict__ Wq, float* __restrict__ Wk)
{
    int idx = blockIdx.x * 256 + threadIdx.x;  // < ZK*256 exactly
    int r = idx >> 8, c = idx & 255;
    Wq[idx] = (r < 258) ? qW[r * 256 + c] : 0.f;
    Wk[idx] = (r < 258) ? kW[r * 256 + c] : 0.f;
}

// W_vo = v_W @ out_W (padded to ZK rows), bvo = v_b @ out_W
__global__ __launch_bounds__(256) void k_prep_vo(const float* __restrict__ vW,
    const float* __restrict__ vb, const float* __restrict__ outW,
    float* __restrict__ Wvo, float* __restrict__ bvo)
{
    int idx = blockIdx.x * 256 + threadIdx.x;
    if (idx < ZK * 8) {
        int r = idx >> 3, e = idx & 7;
        float s = 0.f;
        if (r < 258)
            for (int c = 0; c < 256; ++c) s = fmaf(vW[r * 256 + c], outW[c * 8 + e], s);
        Wvo[idx] = s;
    } else if (idx < ZK * 8 + 8) {
        int e = idx - ZK * 8;
        float s = 0.f;
        for (int c = 0; c < 256; ++c) s = fmaf(vb[c], outW[c * 8 + e], s);
        bvo[e] = s;
    }
}

// expert weights -> bf16, transposed to [out][in] so B-frags load contiguous
__global__ __launch_bounds__(256) void k_prep_w(const float* __restrict__ eWh,
    const float* __restrict__ eWo, unsigned short* __restrict__ Bth,
    unsigned short* __restrict__ Bto)
{
    int id = blockIdx.x * 256 + threadIdx.x;
    if (id < 16 * 65536) {
        int h = id & 255, kcol = (id >> 8) & 255, m = id >> 16;  // m = e*2+l
        Bth[id] = f2bf(eWh[((size_t)m * 256 + h) * 256 + kcol]);
    } else if (id < 24 * 65536) {
        int j = id - 16 * 65536;
        int h = j & 255, o = (j >> 8) & 255, e = j >> 16;
        Bto[j] = f2bf(eWo[((size_t)e * 256 + h) * 256 + o]);
    }
}

// ------------------------------------------------------------- fp32 GEMM
// (router q/k only) C[M,N] = A[M,K] @ B[K,N] + bias ; BM=128 BN=64 BK=32
__global__ __launch_bounds__(256) void k_gemm(
    const float* __restrict__ A, const float* __restrict__ B,
    const float* __restrict__ bias, float* __restrict__ C,
    int K, int lda, int ldb, int ldc)
{
    __shared__ float As[32][132];
    __shared__ float Bs[32][68];
    int t = threadIdx.x;
    int m0 = blockIdx.y * 128, n0 = blockIdx.x * 64;
    int tr = t & 15, tc = t >> 4;
    float acc[8][4];
#pragma unroll
    for (int i = 0; i < 8; ++i)
#pragma unroll
        for (int j = 0; j < 4; ++j) acc[i][j] = 0.f;

    for (int k0 = 0; k0 < K; k0 += 32) {
#pragma unroll
        for (int i = 0; i < 4; ++i) {
            int f = t + 256 * i;
            int kc = f & 7, row = f >> 3;
            float4 v = *(const float4*)&A[(size_t)(m0 + row) * lda + k0 + 4 * kc];
            As[4 * kc + 0][row] = v.x; As[4 * kc + 1][row] = v.y;
            As[4 * kc + 2][row] = v.z; As[4 * kc + 3][row] = v.w;
        }
#pragma unroll
        for (int i = 0; i < 2; ++i) {
            int f = t + 256 * i;
            int nc = f & 15, krow = f >> 4;
            *(float4*)&Bs[krow][4 * nc] =
                *(const float4*)&B[(size_t)(k0 + krow) * ldb + n0 + 4 * nc];
        }
        __syncthreads();
#pragma unroll
        for (int kk = 0; kk < 32; ++kk) {
            float4 a0 = *(const float4*)&As[kk][4 * tr];
            float4 a1 = *(const float4*)&As[kk][64 + 4 * tr];
            float4 b  = *(const float4*)&Bs[kk][4 * tc];
            const float av0[4] = {a0.x, a0.y, a0.z, a0.w};
            const float av1[4] = {a1.x, a1.y, a1.z, a1.w};
            const float bv[4]  = {b.x, b.y, b.z, b.w};
#pragma unroll
            for (int i = 0; i < 4; ++i)
#pragma unroll
                for (int j = 0; j < 4; ++j) {
                    acc[i][j]     = fmaf(av0[i], bv[j], acc[i][j]);
                    acc[4 + i][j] = fmaf(av1[i], bv[j], acc[4 + i][j]);
                }
        }
        __syncthreads();
    }
    float4 bi = *(const float4*)&bias[n0 + 4 * tc];
#pragma unroll
    for (int h = 0; h < 2; ++h)
#pragma unroll
        for (int i = 0; i < 4; ++i) {
            int m = m0 + h * 64 + 4 * tr + i;
            float4 o;
            o.x = acc[h * 4 + i][0] + bi.x;
            o.y = acc[h * 4 + i][1] + bi.y;
            o.z = acc[h * 4 + i][2] + bi.z;
            o.w = acc[h * 4 + i][3] + bi.w;
            *(float4*)&C[(size_t)m * ldc + n0 + 4 * tc] = o;
        }
}

// ----------------------------------------------------- bf16 MFMA GEMM
// C = act(A[M,256] @ B[256,256] + bias); A bf16 row-major, B given TRANSPOSED
// bf16 [out=256][in=256]. BM=128 BN=64, 4 waves as 2x2, wave tile 64x32,
// mfma_f32_16x16x32_bf16. mode 0: relu -> bf16 Cb. mode 1: Cf += w*(acc+bias).
__global__ __launch_bounds__(256) void k_gemm_bf(
    const unsigned short* __restrict__ A,
    const unsigned short* __restrict__ Bt,
    const float* __restrict__ bias,
    unsigned short* __restrict__ Cb,
    float* __restrict__ Cf,
    const float* __restrict__ sparse,
    long long btStrideZ, long long cStrideZ, int biasStrideZ,
    int mode, int expert)
{
    Bt   += (size_t)blockIdx.z * btStrideZ;
    bias += (size_t)blockIdx.z * biasStrideZ;
    if (mode == 0) Cb += (size_t)blockIdx.z * cStrideZ;
    __shared__ unsigned short As[128][40];   // pad 32->40: banks spread
    __shared__ unsigned short Bs[64][40];
    const int t = threadIdx.x;
    const int m0 = blockIdx.y * 128, n0 = blockIdx.x * 64;
    const int wid = t >> 6, lane = t & 63;
    const int wr = wid >> 1, wc = wid & 1;
    const int lr = lane & 15, lg = lane >> 4;
    f32x4 acc[4][2];
#pragma unroll
    for (int mf = 0; mf < 4; ++mf)
#pragma unroll
        for (int nf = 0; nf < 2; ++nf) acc[mf][nf] = (f32x4){0.f, 0.f, 0.f, 0.f};

    const int rA0 = t >> 2, cA0 = t & 3;          // rows 0..63
    const int rB = t >> 2, cB = t & 3;            // Bs rows 0..63
    for (int k0 = 0; k0 < 256; k0 += 32) {
        uint4 va = *(const uint4*)&A[(size_t)(m0 + rA0) * 256 + k0 + 8 * cA0];
        uint4 vb = *(const uint4*)&A[(size_t)(m0 + 64 + rA0) * 256 + k0 + 8 * cA0];
        uint4 vB = *(const uint4*)&Bt[(size_t)(n0 + rB) * 256 + k0 + 8 * cB];
        *(uint4*)&As[rA0][8 * cA0] = va;
        *(uint4*)&As[64 + rA0][8 * cA0] = vb;
        *(uint4*)&Bs[rB][8 * cB] = vB;
        __syncthreads();
        bf16x8 a[4], b[2];
#pragma unroll
        for (int mf = 0; mf < 4; ++mf)
            a[mf] = *(const bf16x8*)&As[wr * 64 + mf * 16 + lr][8 * lg];
#pragma unroll
        for (int nf = 0; nf < 2; ++nf)
            b[nf] = *(const bf16x8*)&Bs[wc * 32 + nf * 16 + lr][8 * lg];
#pragma unroll
        for (int mf = 0; mf < 4; ++mf)
#pragma unroll
            for (int nf = 0; nf < 2; ++nf)
                acc[mf][nf] = __builtin_amdgcn_mfma_f32_16x16x32_bf16(
                    a[mf], b[nf], acc[mf][nf], 0, 0, 0);
        __syncthreads();
    }
    if (mode == 0) {
#pragma unroll
        for (int mf = 0; mf < 4; ++mf)
#pragma unroll
            for (int reg = 0; reg < 4; ++reg) {
                int m = m0 + wr * 64 + mf * 16 + lg * 4 + reg;
#pragma unroll
                for (int nf = 0; nf < 2; ++nf) {
                    int c = n0 + wc * 32 + nf * 16 + lr;
                    float v = acc[mf][nf][reg] + bias[c];
                    Cb[(size_t)m * 256 + c] = f2bf(fmaxf(v, 0.f));
                }
            }
    } else {
#pragma unroll
        for (int mf = 0; mf < 4; ++mf)
#pragma unroll
            for (int reg = 0; reg < 4; ++reg) {
                int m = m0 + wr * 64 + mf * 16 + lg * 4 + reg;
                float w = sparse[m * 8 + expert];
                if (w != 0.f) {
#pragma unroll
                    for (int nf = 0; nf < 2; ++nf) {
                        int c = n0 + wc * 32 + nf * 16 + lr;
                        float v = acc[mf][nf][reg] + bias[c];
                        Cf[(size_t)m * 256 + c] += w * v;
                    }
                }
            }
    }
}

// ------------------------------------------------------------- vo = z @ Wvo
__global__ __launch_bounds__(256) void k_vo(const float* __restrict__ z,
    const float* __restrict__ Wvo, const float* __restrict__ bvo,
    float* __restrict__ vo)
{
    int n = blockIdx.x * 4 + (threadIdx.x >> 6);
    int lane = threadIdx.x & 63;
    float p[8];
#pragma unroll
    for (int e = 0; e < 8; ++e) p[e] = 0.f;
    for (int kk = lane; kk < ZK; kk += 64) {
        float zv = z[(size_t)n * ZK + kk];
        float4 w0 = *(const float4*)&Wvo[kk * 8];
        float4 w1 = *(const float4*)&Wvo[kk * 8 + 4];
        p[0] = fmaf(zv, w0.x, p[0]); p[1] = fmaf(zv, w0.y, p[1]);
        p[2] = fmaf(zv, w0.z, p[2]); p[3] = fmaf(zv, w0.w, p[3]);
        p[4] = fmaf(zv, w1.x, p[4]); p[5] = fmaf(zv, w1.y, p[5]);
        p[6] = fmaf(zv, w1.z, p[6]); p[7] = fmaf(zv, w1.w, p[7]);
    }
#pragma unroll
    for (int msk = 1; msk <= 32; msk <<= 1)
#pragma unroll
        for (int e = 0; e < 8; ++e) p[e] += __shfl_xor(p[e], msk);
    if (lane == 0) {
#pragma unroll
        for (int e = 0; e < 8; ++e) vo[n * 8 + e] = p[e] + bvo[e];
    }
}

// -------------------------------------- flash attention (fp32) with 8-col PV
// 32 q-rows per block, split-K=3 (chunks 11/11/10 of 256 rows).
__global__ __launch_bounds__(256) void k_attn(
    const float* __restrict__ q, const float* __restrict__ k,
    const float* __restrict__ vo, float* __restrict__ pm,
    float* __restrict__ pl, float* __restrict__ pacc, float scale)
{
    __shared__ float qt[256][36];
    __shared__ float wred[4][36];
    __shared__ float lred[4][36];
    __shared__ float pvred[4][32][8];
    __shared__ float mst[32], lst[32], accst[32][8];
    const int t = threadIdx.x;
    const int n0 = blockIdx.x * 32;
    const int split = blockIdx.y;
    for (int i = t; i < 32 * 256; i += 256) {
        int r = i >> 8, d = i & 255;
        qt[d][r] = q[(size_t)(n0 + r) * 256 + d] * scale;
    }
    if (t < 32) {
        mst[t] = -INFINITY; lst[t] = 0.f;
#pragma unroll
        for (int e = 0; e < 8; ++e) accst[t][e] = 0.f;
    }
    __syncthreads();
    const int tr = t & 7, tc = t >> 3;
    const int wv = t >> 6, lane = t & 63;
    const int chStart = split * 11;
    const int chEnd = (split == 2) ? 32 : chStart + 11;

    for (int ch = chStart; ch < chEnd; ++ch) {
        const int krbase = ch * 256 + 8 * tc;
        const float* kp = k + (size_t)krbase * 256;
        float s[4][8];
#pragma unroll
        for (int i = 0; i < 4; ++i)
#pragma unroll
            for (int j = 0; j < 8; ++j) s[i][j] = 0.f;
#pragma unroll 4
        for (int d0 = 0; d0 < 256; d0 += 4) {
            float4 q0 = *(const float4*)&qt[d0 + 0][4 * tr];
            float4 q1 = *(const float4*)&qt[d0 + 1][4 * tr];
            float4 q2 = *(const float4*)&qt[d0 + 2][4 * tr];
            float4 q3 = *(const float4*)&qt[d0 + 3][4 * tr];
#pragma unroll
            for (int j = 0; j < 8; ++j) {
                float4 kv = *(const float4*)&kp[j * 256 + d0];
                s[0][j] = fmaf(q0.x, kv.x, s[0][j]); s[0][j] = fmaf(q1.x, kv.y, s[0][j]);
                s[0][j] = fmaf(q2.x, kv.z, s[0][j]); s[0][j] = fmaf(q3.x, kv.w, s[0][j]);
                s[1][j] = fmaf(q0.y, kv.x, s[1][j]); s[1][j] = fmaf(q1.y, kv.y, s[1][j]);
                s[1][j] = fmaf(q2.y, kv.z, s[1][j]); s[1][j] = fmaf(q3.y, kv.w, s[1][j]);
                s[2][j] = fmaf(q0.z, kv.x, s[2][j]); s[2][j] = fmaf(q1.z, kv.y, s[2][j]);
                s[2][j] = fmaf(q2.z, kv.z, s[2][j]); s[2][j] = fmaf(q3.z, kv.w, s[2][j]);
                s[3][j] = fmaf(q0.w, kv.x, s[3][j]); s[3][j] = fmaf(q1.w, kv.y, s[3][j]);
                s[3][j] = fmaf(q2.w, kv.z, s[3][j]); s[3][j] = fmaf(q3.w, kv.w, s[3][j]);
            }
        }
        // --- online softmax bookkeeping ---
        float tm[4];
#pragma unroll
        for (int i = 0; i < 4; ++i) {
            float a = fmaxf(fmaxf(s[i][0], s[i][1]), fmaxf(s[i][2], s[i][3]));
            float b = fmaxf(fmaxf(s[i][4], s[i][5]), fmaxf(s[i][6], s[i][7]));
            tm[i] = fmaxf(a, b);
        }
#pragma unroll
        for (int msk = 8; msk <= 32; msk <<= 1)
#pragma unroll
            for (int i = 0; i < 4; ++i) tm[i] = fmaxf(tm[i], __shfl_xor(tm[i], msk));
        if (lane < 8) {
#pragma unroll
            for (int i = 0; i < 4; ++i) wred[wv][4 * lane + i] = tm[i];
        }
        __syncthreads();
        float mnew[4];
#pragma unroll
        for (int i = 0; i < 4; ++i) {
            int r = 4 * tr + i;
            float tmax = fmaxf(fmaxf(wred[0][r], wred[1][r]), fmaxf(wred[2][r], wred[3][r]));
            mnew[i] = fmaxf(mst[r], tmax);
        }
        float ps[4] = {0.f, 0.f, 0.f, 0.f};
        float pv[4][8];
#pragma unroll
        for (int i = 0; i < 4; ++i)
#pragma unroll
            for (int e = 0; e < 8; ++e) pv[i][e] = 0.f;
#pragma unroll
        for (int j = 0; j < 8; ++j) {
            int kr = krbase + j;
            float4 va = *(const float4*)&vo[kr * 8];
            float4 vb4 = *(const float4*)&vo[kr * 8 + 4];
#pragma unroll
            for (int i = 0; i < 4; ++i) {
                float p = __expf(s[i][j] - mnew[i]);
                ps[i] += p;
                pv[i][0] = fmaf(p, va.x, pv[i][0]);  pv[i][1] = fmaf(p, va.y, pv[i][1]);
                pv[i][2] = fmaf(p, va.z, pv[i][2]);  pv[i][3] = fmaf(p, va.w, pv[i][3]);
                pv[i][4] = fmaf(p, vb4.x, pv[i][4]); pv[i][5] = fmaf(p, vb4.y, pv[i][5]);
                pv[i][6] = fmaf(p, vb4.z, pv[i][6]); pv[i][7] = fmaf(p, vb4.w, pv[i][7]);
            }
        }
#pragma unroll
        for (int msk = 8; msk <= 32; msk <<= 1) {
#pragma unroll
            for (int i = 0; i < 4; ++i) {
                ps[i] += __shfl_xor(ps[i], msk);
#pragma unroll
                for (int e = 0; e < 8; ++e) pv[i][e] += __shfl_xor(pv[i][e], msk);
            }
        }
        if (lane < 8) {
#pragma unroll
            for (int i = 0; i < 4; ++i) {
                lred[wv][4 * lane + i] = ps[i];
#pragma unroll
                for (int e = 0; e < 8; ++e) pvred[wv][4 * lane + i][e] = pv[i][e];
            }
        }
        __syncthreads();
        if (t < 32) {
            int r = t;
            float tmax = fmaxf(fmaxf(wred[0][r], wred[1][r]), fmaxf(wred[2][r], wred[3][r]));
            float mo = mst[r];
            float mn = fmaxf(mo, tmax);
            float rs = __expf(mo - mn);
            lst[r] = lst[r] * rs + (lred[0][r] + lred[1][r] + lred[2][r] + lred[3][r]);
            mst[r] = mn;
#pragma unroll
            for (int e = 0; e < 8; ++e)
                accst[r][e] = accst[r][e] * rs +
                    (pvred[0][r][e] + pvred[1][r][e] + pvred[2][r][e] + pvred[3][r][e]);
        }
        __syncthreads();
    }
    if (t < 32) {
        int n = n0 + t;
        pm[split * NN + n] = mst[t];
        pl[split * NN + n] = lst[t];
#pragma unroll
        for (int e = 0; e < 8; ++e) pacc[(size_t)split * NN * 8 + n * 8 + e] = accst[t][e];
    }
}

// ----------------------------------- merge split-K partials -> top2 weights
__global__ __launch_bounds__(256) void k_attn_merge(
    const float* __restrict__ pm, const float* __restrict__ pl,
    const float* __restrict__ pacc, const float* __restrict__ outb,
    float* __restrict__ sparse)
{
    int n = blockIdx.x * 256 + threadIdx.x;
    float mn = -INFINITY;
#pragma unroll
    for (int s = 0; s < NSPLIT; ++s) mn = fmaxf(mn, pm[s * NN + n]);
    float l = 0.f;
    float lg[8];
#pragma unroll
    for (int e = 0; e < 8; ++e) lg[e] = 0.f;
#pragma unroll
    for (int s = 0; s < NSPLIT; ++s) {
        float r = __expf(pm[s * NN + n] - mn);
        l += pl[s * NN + n] * r;
#pragma unroll
        for (int e = 0; e < 8; ++e)
            lg[e] += pacc[(size_t)s * NN * 8 + n * 8 + e] * r;
    }
    float inv = 1.f / l;
#pragma unroll
    for (int e = 0; e < 8; ++e) lg[e] = lg[e] * inv + outb[e];
    int i1 = 0; float v1 = lg[0];
#pragma unroll
    for (int e = 1; e < 8; ++e) if (lg[e] > v1) { v1 = lg[e]; i1 = e; }
    int i2 = -1; float v2 = -INFINITY;
#pragma unroll
    for (int e = 0; e < 8; ++e) if (e != i1 && lg[e] > v2) { v2 = lg[e]; i2 = e; }
    float e2 = __expf(v2 - v1);
    float w1 = 1.f / (1.f + e2);
    float w2 = e2 / (1.f + e2);
#pragma unroll
    for (int e = 0; e < 8; ++e)
        sparse[n * 8 + e] = (e == i1) ? w1 : ((e == i2) ? w2 : 0.f);
}

// ------------------- X = bf16(He + neigh_mean(He)), fp32 source (z) variant
__global__ __launch_bounds__(256) void k_agg_f2b(
    const float* __restrict__ src, const int* __restrict__ rowptr,
    const int* __restrict__ colidx, unsigned short* __restrict__ X)
{
    int n = blockIdx.x * 4 + (threadIdx.x >> 6);
    int c4 = (threadIdx.x & 63) * 4;
    int r0 = rowptr[n], r1 = rowptr[n + 1];
    float a0 = 0.f, a1 = 0.f, a2 = 0.f, a3 = 0.f;
    for (int i = r0; i < r1; ++i) {
        int sn = colidx[i];
        float4 v = *(const float4*)&src[(size_t)sn * ZK + c4];
        a0 += v.x; a1 += v.y; a2 += v.z; a3 += v.w;
    }
    int deg = r1 - r0;
    float inv = 1.f / (float)(deg > 1 ? deg : 1);
    float4 self = *(const float4*)&src[(size_t)n * ZK + c4];
    ushort4 o;
    o.x = f2bf(self.x + a0 * inv); o.y = f2bf(self.y + a1 * inv);
    o.z = f2bf(self.z + a2 * inv); o.w = f2bf(self.w + a3 * inv);
    *(ushort4*)&X[(size_t)n * 256 + c4] = o;
}

// ------------------------------------------------ bf16 source (He) variant
__global__ __launch_bounds__(256) void k_agg_b2b(
    const unsigned short* __restrict__ He, const int* __restrict__ rowptr,
    const int* __restrict__ colidx, unsigned short* __restrict__ X)
{
    int n = blockIdx.x * 4 + (threadIdx.x >> 6);
    int c4 = (threadIdx.x & 63) * 4;
    int r0 = rowptr[n], r1 = rowptr[n + 1];
    float a0 = 0.f, a1 = 0.f, a2 = 0.f, a3 = 0.f;
    for (int i = r0; i < r1; ++i) {
        int sn = colidx[i];
        ushort4 v = *(const ushort4*)&He[(size_t)sn * 256 + c4];
        a0 += b2f(v.x); a1 += b2f(v.y); a2 += b2f(v.z); a3 += b2f(v.w);
    }
    int deg = r1 - r0;
    float inv = 1.f / (float)(deg > 1 ? deg : 1);
    ushort4 self = *(const ushort4*)&He[(size_t)n * 256 + c4];
    ushort4 o;
    o.x = f2bf(b2f(self.x) + a0 * inv); o.y = f2bf(b2f(self.y) + a1 * inv);
    o.z = f2bf(b2f(self.z) + a2 * inv); o.w = f2bf(b2f(self.w) + a3 * inv);
    *(ushort4*)&X[(size_t)n * 256 + c4] = o;
}

// ==========================================================================
extern "C" void kernel_launch(void* const* d_in, const int* in_sizes, int n_in,
                              void* d_out, int out_size, void* d_ws, size_t ws_size,
                              hipStream_t stream)
{
    (void)n_in; (void)out_size;
    const float* x     = (const float*)d_in[0];
    const int*   ei    = (const int*)d_in[1];
    const int*   batch = (const int*)d_in[2];
    const float* encW  = (const float*)d_in[3];
    const float* encb  = (const float*)d_in[4];
    const float* qW    = (const float*)d_in[5];
    const float* qb    = (const float*)d_in[6];
    const float* kW    = (const float*)d_in[7];
    const float* kb    = (const float*)d_in[8];
    const float* vW    = (const float*)d_in[9];
    const float* vb    = (const float*)d_in[10];
    const float* outW  = (const float*)d_in[11];
    const float* outb  = (const float*)d_in[12];
    const float* eWh   = (const float*)d_in[13];
    const float* ebh   = (const float*)d_in[14];
    const float* eWo   = (const float*)d_in[15];
    const float* ebo   = (const float*)d_in[16];
    float* out = (float*)d_out;
    if (in_sizes[0] != NN * 6 || in_sizes[1] != 2 * NE) return;

    char* wsp = (char*)d_ws;
    size_t off = 0;
    auto alloc = [&](size_t bytes) -> void* {
        void* p = wsp + off;
        off += (bytes + 511) & ~(size_t)511;
        return p;
    };
    float* z      = (float*)alloc((size_t)NN * ZK * 4);
    float* qbuf   = (float*)alloc((size_t)NN * 256 * 4);
    float* kbuf   = (float*)alloc((size_t)NN * 256 * 4);
    float* vo     = (float*)alloc((size_t)NN * 8 * 4);
    float* sparse = (float*)alloc((size_t)NN * 8 * 4);
    unsigned short* Xb  = (unsigned short*)alloc((size_t)NN * 256 * 2);
    unsigned short* Heb = (unsigned short*)alloc((size_t)8 * NN * 256 * 2);
    unsigned short* Bth = (unsigned short*)alloc((size_t)16 * 65536 * 2);
    unsigned short* Bto = (unsigned short*)alloc((size_t)8 * 65536 * 2);
    float* Wq     = (float*)alloc((size_t)ZK * 256 * 4);
    float* Wk     = (float*)alloc((size_t)ZK * 256 * 4);
    float* Wvo    = (float*)alloc((size_t)ZK * 8 * 4);
    float* bvo    = (float*)alloc(8 * 4);
    float* pm     = (float*)alloc((size_t)NSPLIT * NN * 4);
    float* pl     = (float*)alloc((size_t)NSPLIT * NN * 4);
    float* pacc   = (float*)alloc((size_t)NSPLIT * NN * 8 * 4);
    int* ints     = (int*)alloc((size_t)(NG + NG + NN + NN) * 4);
    int* ncnt = ints, *ecnt = ints + NG, *indeg = ecnt + NG, *cursor = indeg + NN;
    int* rowptr   = (int*)alloc((size_t)(NN + 1) * 4);
    int* colidx   = (int*)alloc((size_t)NE * 4);
    if (off > ws_size) return;  // workspace too small -> fail visibly

    hipMemsetAsync(ints, 0, (size_t)(NG + NG + NN + NN) * 4, stream);
    hipMemsetAsync(out, 0, (size_t)NN * 256 * 4, stream);
    k_counts<<<(NE + 255) / 256, 256, 0, stream>>>(ei, batch, ncnt, ecnt, indeg);
    k_prep_qk<<<ZK, 256, 0, stream>>>(qW, kW, Wq, Wk);
    k_prep_vo<<<(ZK * 8 + 8 + 255) / 256, 256, 0, stream>>>(vW, vb, outW, Wvo, bvo);
    k_prep_w<<<(24 * 65536) / 256, 256, 0, stream>>>(eWh, eWo, Bth, Bto);
    k_encoder<<<NN, 256, 0, stream>>>(x, encW, encb, batch, ncnt, ecnt, z);
    k_scan<<<1, 256, 0, stream>>>(indeg, rowptr);
    k_fill<<<(NE + 255) / 256, 256, 0, stream>>>(ei, rowptr, cursor, colidx);

    dim3 g1(256 / 64, NN / 128, 1);
    k_gemm<<<g1, 256, 0, stream>>>(z, Wq, qb, qbuf, ZK, ZK, 256, 256);
    k_gemm<<<g1, 256, 0, stream>>>(z, Wk, kb, kbuf, ZK, ZK, 256, 256);
    k_vo<<<NN / 4, 256, 0, stream>>>(z, Wvo, bvo, vo);

    float scale = 1.f / sqrtf(258.f);
    dim3 ga(NN / 32, NSPLIT, 1);
    k_attn<<<ga, 256, 0, stream>>>(qbuf, kbuf, vo, pm, pl, pacc, scale);
    k_attn_merge<<<NN / 256, 256, 0, stream>>>(pm, pl, pacc, outb, sparse);

    // ---- experts (bf16 MFMA towers) ----
    k_agg_f2b<<<NN / 4, 256, 0, stream>>>(z, rowptr, colidx, Xb);
    // layer 1: shared A, batched over 8 experts
    dim3 gb8(256 / 64, NN / 128, 8);
    k_gemm_bf<<<gb8, 256, 0, stream>>>(Xb, Bth, ebh, Heb, nullptr, nullptr,
                                       (long long)2 * 65536, (long long)NN * 256,
                                       2 * 256, 0, 0);
    dim3 gb1(256 / 64, NN / 128, 1);
    // layer 2
    for (int e = 0; e < 8; ++e) {
        k_agg_b2b<<<NN / 4, 256, 0, stream>>>(Heb + (size_t)e * NN * 256, rowptr, colidx, Xb);
        k_gemm_bf<<<gb1, 256, 0, stream>>>(Xb, Bth + (size_t)(e * 2 + 1) * 65536,
                                           ebh + (e * 2 + 1) * 256,
                                           Heb + (size_t)e * NN * 256, nullptr, nullptr,
                                           0, 0, 0, 0, 0);
    }
    // layer 3 (output): fused top-2 weighted accumulate into d_out
    for (int e = 0; e < 8; ++e) {
        k_agg_b2b<<<NN / 4, 256, 0, stream>>>(Heb + (size_t)e * NN * 256, rowptr, colidx, Xb);
        k_gemm_bf<<<gb1, 256, 0, stream>>>(Xb, Bto + (size_t)e * 65536, ebo + e * 256,
                                           nullptr, out, sparse, 0, 0, 0, 1, e);
    }
}

// Round 3
// 756.901 us; speedup vs baseline: 2.4740x; 1.9610x over previous
//
#include <hip/hip_runtime.h>
#include <math.h>

#define NN 8192      // nodes
#define NE 131072    // edges
#define ZK 288       // padded z width (258 -> 288, multiple of 32)
#define NG 64        // graphs
#define ASPLIT 4     // attention split-K
#define QB 64        // q-rows per attention block
#define KB 32        // keys per attention chunk

typedef __attribute__((ext_vector_type(8))) short bf16x8;
typedef __attribute__((ext_vector_type(4))) float f32x4;
typedef __attribute__((ext_vector_type(8))) _Float16 f16x8;
typedef __attribute__((ext_vector_type(4))) _Float16 f16x4;

static __device__ __forceinline__ unsigned short f2bf(float f) {
    unsigned u = __float_as_uint(f);
    unsigned r = (u + 0x7FFFu + ((u >> 16) & 1u)) >> 16;   // RNE
    return (unsigned short)r;
}
static __device__ __forceinline__ float b2f(unsigned short h) {
    return __uint_as_float(((unsigned)h) << 16);
}

// ---------------------------------------------------------------- counts
__global__ __launch_bounds__(256) void k_counts(const int* __restrict__ ei,
    const int* __restrict__ batch, int* ncnt, int* ecnt, int* indeg)
{
    int tid = blockIdx.x * 256 + threadIdx.x;
    if (tid < NE) {
        int src = ei[tid], dst = ei[NE + tid];
        atomicAdd(&ecnt[batch[src]], 1);
        atomicAdd(&indeg[dst], 1);
    }
    if (tid < NN) atomicAdd(&ncnt[batch[tid]], 1);
}

// ------------------------------------------------- encoder + size feats -> z
__global__ __launch_bounds__(256) void k_encoder(const float* __restrict__ x,
    const float* __restrict__ encW, const float* __restrict__ encb,
    const int* __restrict__ batch, const int* __restrict__ ncnt,
    const int* __restrict__ ecnt, float* __restrict__ z)
{
    int n = blockIdx.x, c = threadIdx.x;
    __shared__ float xr[8];
    if (c < 6) xr[c] = x[n * 6 + c];
    __syncthreads();
    float a = encb[c];
#pragma unroll
    for (int i = 0; i < 6; ++i) a = fmaf(xr[i], encW[i * 256 + c], a);
    z[n * ZK + c] = fmaxf(a, 0.f);
    if (c == 0) {
        int g = batch[n];
        z[n * ZK + 256] = log1pf((float)ncnt[g]);
        z[n * ZK + 257] = log1pf((float)ecnt[g]);
    }
    if (c >= 2 && c < 32) z[n * ZK + 256 + c] = 0.f;  // zero pad 258..287
}

// ---------------------------------------------------------------- CSR build
__global__ __launch_bounds__(256) void k_scan(const int* __restrict__ indeg,
                                              int* __restrict__ rowptr)
{
    __shared__ int part[256];
    int t = threadIdx.x;
    int base = t * 32, s = 0;
    for (int i = 0; i < 32; ++i) s += indeg[base + i];
    part[t] = s;
    __syncthreads();
    if (t == 0) {
        int run = 0;
        for (int i = 0; i < 256; ++i) { int v = part[i]; part[i] = run; run += v; }
        rowptr[NN] = run;
    }
    __syncthreads();
    int run = part[t];
    for (int i = 0; i < 32; ++i) { rowptr[base + i] = run; run += indeg[base + i]; }
}

__global__ __launch_bounds__(256) void k_fill(const int* __restrict__ ei,
    const int* __restrict__ rowptr, int* __restrict__ cursor, int* __restrict__ colidx)
{
    int tid = blockIdx.x * 256 + threadIdx.x;
    if (tid >= NE) return;
    int dst = ei[NE + tid];
    int pos = atomicAdd(&cursor[dst], 1);
    colidx[rowptr[dst] + pos] = ei[tid];
}

// ------------------------------------------------------- weight preparation
__global__ __launch_bounds__(256) void k_prep_qk(const float* __restrict__ qW,
    const float* __restrict__ kW, float* __restrict__ Wq, float* __restrict__ Wk)
{
    int idx = blockIdx.x * 256 + threadIdx.x;  // < ZK*256 exactly
    int r = idx >> 8, c = idx & 255;
    Wq[idx] = (r < 258) ? qW[r * 256 + c] : 0.f;
    Wk[idx] = (r < 258) ? kW[r * 256 + c] : 0.f;
}

// W_vo = v_W @ out_W (padded to ZK rows), bvo = v_b @ out_W
__global__ __launch_bounds__(256) void k_prep_vo(const float* __restrict__ vW,
    const float* __restrict__ vb, const float* __restrict__ outW,
    float* __restrict__ Wvo, float* __restrict__ bvo)
{
    int idx = blockIdx.x * 256 + threadIdx.x;
    if (idx < ZK * 8) {
        int r = idx >> 3, e = idx & 7;
        float s = 0.f;
        if (r < 258)
            for (int c = 0; c < 256; ++c) s = fmaf(vW[r * 256 + c], outW[c * 8 + e], s);
        Wvo[idx] = s;
    } else if (idx < ZK * 8 + 8) {
        int e = idx - ZK * 8;
        float s = 0.f;
        for (int c = 0; c < 256; ++c) s = fmaf(vb[c], outW[c * 8 + e], s);
        bvo[e] = s;
    }
}

// expert weights -> bf16, transposed to [out][in] so B-frags load contiguous
__global__ __launch_bounds__(256) void k_prep_w(const float* __restrict__ eWh,
    const float* __restrict__ eWo, unsigned short* __restrict__ Bth,
    unsigned short* __restrict__ Bto)
{
    int id = blockIdx.x * 256 + threadIdx.x;
    if (id < 16 * 65536) {
        int h = id & 255, kcol = (id >> 8) & 255, m = id >> 16;  // m = e*2+l
        Bth[id] = f2bf(eWh[((size_t)m * 256 + h) * 256 + kcol]);
    } else if (id < 24 * 65536) {
        int j = id - 16 * 65536;
        int h = j & 255, o = (j >> 8) & 255, e = j >> 16;
        Bto[j] = f2bf(eWo[((size_t)e * 256 + h) * 256 + o]);
    }
}

// ------------------------------- fp32 GEMM writing split-fp16 (hi,lo) output
// C(hi,lo) = (A[M,K] @ B[K,N] + bias) * scl ; BM=128 BN=64 BK=32
__global__ __launch_bounds__(256) void k_gemm_qk(
    const float* __restrict__ A, const float* __restrict__ B,
    const float* __restrict__ bias, _Float16* __restrict__ Ch,
    _Float16* __restrict__ Cl, float scl, int K)
{
    __shared__ float As[32][132];
    __shared__ float Bs[32][68];
    int t = threadIdx.x;
    int m0 = blockIdx.y * 128, n0 = blockIdx.x * 64;
    int tr = t & 15, tc = t >> 4;
    float acc[8][4];
#pragma unroll
    for (int i = 0; i < 8; ++i)
#pragma unroll
        for (int j = 0; j < 4; ++j) acc[i][j] = 0.f;

    for (int k0 = 0; k0 < K; k0 += 32) {
#pragma unroll
        for (int i = 0; i < 4; ++i) {
            int f = t + 256 * i;
            int kc = f & 7, row = f >> 3;
            float4 v = *(const float4*)&A[(size_t)(m0 + row) * ZK + k0 + 4 * kc];
            As[4 * kc + 0][row] = v.x; As[4 * kc + 1][row] = v.y;
            As[4 * kc + 2][row] = v.z; As[4 * kc + 3][row] = v.w;
        }
#pragma unroll
        for (int i = 0; i < 2; ++i) {
            int f = t + 256 * i;
            int nc = f & 15, krow = f >> 4;
            *(float4*)&Bs[krow][4 * nc] =
                *(const float4*)&B[(size_t)(k0 + krow) * 256 + n0 + 4 * nc];
        }
        __syncthreads();
#pragma unroll
        for (int kk = 0; kk < 32; ++kk) {
            float4 a0 = *(const float4*)&As[kk][4 * tr];
            float4 a1 = *(const float4*)&As[kk][64 + 4 * tr];
            float4 b  = *(const float4*)&Bs[kk][4 * tc];
            const float av0[4] = {a0.x, a0.y, a0.z, a0.w};
            const float av1[4] = {a1.x, a1.y, a1.z, a1.w};
            const float bv[4]  = {b.x, b.y, b.z, b.w};
#pragma unroll
            for (int i = 0; i < 4; ++i)
#pragma unroll
                for (int j = 0; j < 4; ++j) {
                    acc[i][j]     = fmaf(av0[i], bv[j], acc[i][j]);
                    acc[4 + i][j] = fmaf(av1[i], bv[j], acc[4 + i][j]);
                }
        }
        __syncthreads();
    }
    float4 bi = *(const float4*)&bias[n0 + 4 * tc];
    const float bb[4] = {bi.x, bi.y, bi.z, bi.w};
#pragma unroll
    for (int h = 0; h < 2; ++h)
#pragma unroll
        for (int i = 0; i < 4; ++i) {
            int m = m0 + h * 64 + 4 * tr + i;
            f16x4 vh, vl;
#pragma unroll
            for (int j = 0; j < 4; ++j) {
                float v = (acc[h * 4 + i][j] + bb[j]) * scl;
                _Float16 hi = (_Float16)v;
                vh[j] = hi;
                vl[j] = (_Float16)(v - (float)hi);
            }
            *(f16x4*)&Ch[(size_t)m * 256 + n0 + 4 * tc] = vh;
            *(f16x4*)&Cl[(size_t)m * 256 + n0 + 4 * tc] = vl;
        }
}

// ----------------------------------------------------- bf16 MFMA GEMM
// C = act(A[M,256] @ B^T + bias); BM=128 BN=64, 4 waves 2x2, 16x16x32.
// mode 0: relu -> bf16 Cb.  mode 1: Ys[slot] = w*(acc+bias) (top-2 slots).
__global__ __launch_bounds__(256) void k_gemm_bf(
    const unsigned short* __restrict__ A,
    const unsigned short* __restrict__ Bt,
    const float* __restrict__ bias,
    unsigned short* __restrict__ Cb,
    float* __restrict__ Ys,
    const float* __restrict__ sparse,
    const int* __restrict__ i1,
    long long aStrideZ, long long btStrideZ, long long cStrideZ, int biasStrideZ,
    int mode)
{
    const int ez = blockIdx.z;
    A    += (size_t)ez * aStrideZ;
    Bt   += (size_t)ez * btStrideZ;
    bias += (size_t)ez * biasStrideZ;
    if (mode == 0) Cb += (size_t)ez * cStrideZ;
    __shared__ unsigned short As[128][40];
    __shared__ unsigned short Bs[64][40];
    const int t = threadIdx.x;
    const int m0 = blockIdx.y * 128, n0 = blockIdx.x * 64;
    const int wid = t >> 6, lane = t & 63;
    const int wr = wid >> 1, wc = wid & 1;
    const int lr = lane & 15, lg = lane >> 4;
    f32x4 acc[4][2];
#pragma unroll
    for (int mf = 0; mf < 4; ++mf)
#pragma unroll
        for (int nf = 0; nf < 2; ++nf) acc[mf][nf] = (f32x4){0.f, 0.f, 0.f, 0.f};

    const int rA0 = t >> 2, cA0 = t & 3;
    for (int k0 = 0; k0 < 256; k0 += 32) {
        uint4 va = *(const uint4*)&A[(size_t)(m0 + rA0) * 256 + k0 + 8 * cA0];
        uint4 vb = *(const uint4*)&A[(size_t)(m0 + 64 + rA0) * 256 + k0 + 8 * cA0];
        uint4 vB = *(const uint4*)&Bt[(size_t)(n0 + rA0) * 256 + k0 + 8 * cA0];
        *(uint4*)&As[rA0][8 * cA0] = va;
        *(uint4*)&As[64 + rA0][8 * cA0] = vb;
        *(uint4*)&Bs[rA0][8 * cA0] = vB;
        __syncthreads();
        bf16x8 a[4], b[2];
#pragma unroll
        for (int mf = 0; mf < 4; ++mf)
            a[mf] = *(const bf16x8*)&As[wr * 64 + mf * 16 + lr][8 * lg];
#pragma unroll
        for (int nf = 0; nf < 2; ++nf)
            b[nf] = *(const bf16x8*)&Bs[wc * 32 + nf * 16 + lr][8 * lg];
#pragma unroll
        for (int mf = 0; mf < 4; ++mf)
#pragma unroll
            for (int nf = 0; nf < 2; ++nf)
                acc[mf][nf] = __builtin_amdgcn_mfma_f32_16x16x32_bf16(
                    a[mf], b[nf], acc[mf][nf], 0, 0, 0);
        __syncthreads();
    }
    if (mode == 0) {
#pragma unroll
        for (int mf = 0; mf < 4; ++mf)
#pragma unroll
            for (int reg = 0; reg < 4; ++reg) {
                int m = m0 + wr * 64 + mf * 16 + lg * 4 + reg;
#pragma unroll
                for (int nf = 0; nf < 2; ++nf) {
                    int c = n0 + wc * 32 + nf * 16 + lr;
                    float v = acc[mf][nf][reg] + bias[c];
                    Cb[(size_t)m * 256 + c] = f2bf(fmaxf(v, 0.f));
                }
            }
    } else {
#pragma unroll
        for (int mf = 0; mf < 4; ++mf)
#pragma unroll
            for (int reg = 0; reg < 4; ++reg) {
                int m = m0 + wr * 64 + mf * 16 + lg * 4 + reg;
                float w = sparse[m * 8 + ez];
                if (w != 0.f) {
                    int slot = (ez == i1[m]) ? 0 : 1;
                    float* dst = Ys + (size_t)slot * NN * 256 + (size_t)m * 256;
#pragma unroll
                    for (int nf = 0; nf < 2; ++nf) {
                        int c = n0 + wc * 32 + nf * 16 + lr;
                        dst[c] = w * (acc[mf][nf][reg] + bias[c]);
                    }
                }
            }
    }
}

// ------------------------------------------------------------- vo = z @ Wvo
__global__ __launch_bounds__(256) void k_vo(const float* __restrict__ z,
    const float* __restrict__ Wvo, const float* __restrict__ bvo,
    float* __restrict__ vo)
{
    int n = blockIdx.x * 4 + (threadIdx.x >> 6);
    int lane = threadIdx.x & 63;
    float p[8];
#pragma unroll
    for (int e = 0; e < 8; ++e) p[e] = 0.f;
    for (int kk = lane; kk < ZK; kk += 64) {
        float zv = z[(size_t)n * ZK + kk];
        float4 w0 = *(const float4*)&Wvo[kk * 8];
        float4 w1 = *(const float4*)&Wvo[kk * 8 + 4];
        p[0] = fmaf(zv, w0.x, p[0]); p[1] = fmaf(zv, w0.y, p[1]);
        p[2] = fmaf(zv, w0.z, p[2]); p[3] = fmaf(zv, w0.w, p[3]);
        p[4] = fmaf(zv, w1.x, p[4]); p[5] = fmaf(zv, w1.y, p[5]);
        p[6] = fmaf(zv, w1.z, p[6]); p[7] = fmaf(zv, w1.w, p[7]);
    }
#pragma unroll
    for (int msk = 1; msk <= 32; msk <<= 1)
#pragma unroll
        for (int e = 0; e < 8; ++e) p[e] += __shfl_xor(p[e], msk);
    if (lane == 0) {
#pragma unroll
        for (int e = 0; e < 8; ++e) vo[n * 8 + e] = p[e] + bvo[e];
    }
}

// ---------------------------------------- split-fp16 MFMA flash attention
// 64 q-rows/block (4 waves x 16 rows), split-K=4, K staged in swizzled LDS.
// s = qh*kh + qh*kl + ql*kh (fp32 MFMA accum). Per-lane private online softmax.
__global__ __launch_bounds__(256, 2) void k_attn_mfma(
    const _Float16* __restrict__ qh, const _Float16* __restrict__ ql,
    const _Float16* __restrict__ kh, const _Float16* __restrict__ kl,
    const float* __restrict__ vo, float* __restrict__ pm,
    float* __restrict__ pl, float* __restrict__ pacc)
{
    __shared__ char lds[2][KB * 1024];   // per key: 512B hi | 512B lo, swizzled
    const int bid = blockIdx.x;
    const int xcd = bid & 7;
    const int split = xcd >> 1;                       // XCD pair owns a split
    const int qblk = ((bid >> 3) << 1) + (xcd & 1);   // 0..127
    const int n0 = qblk * QB;
    const int t = threadIdx.x, w = t >> 6, lane = t & 63;
    const int g = lane >> 4, c = lane & 15;
    const int row = n0 + w * 16 + c;

    // Q A-fragments, persistent in registers
    f16x8 ah[8], al[8];
#pragma unroll
    for (int ks = 0; ks < 8; ++ks) {
        ah[ks] = *(const f16x8*)&qh[(size_t)row * 256 + ks * 32 + g * 8];
        al[ks] = *(const f16x8*)&ql[(size_t)row * 256 + ks * 32 + g * 8];
    }
    float m_[4], l_[4], pv[4][8];
#pragma unroll
    for (int r = 0; r < 4; ++r) {
        m_[r] = -INFINITY; l_[r] = 0.f;
#pragma unroll
        for (int e = 0; e < 8; ++e) pv[r][e] = 0.f;
    }
    const int kbase0 = split * 2048;

    // stage chunk: 32 keys x (512B hi + 512B lo), 16B-unit XOR swizzle by key
    auto stage = [&](char* buf, int kb) {
#pragma unroll
        for (int i = 0; i < 8; ++i) {
            int u = i * 256 + t;
            int key = u >> 6, ur = u & 63;
            int half = ur >> 5, c16 = ur & 31;
            const _Float16* src = half ? kl : kh;
            uint4 v = *(const uint4*)&src[(size_t)(kb + key) * 256 + c16 * 8];
            int dst = key * 1024 + half * 512 + ((c16 * 16) ^ ((key & 7) << 4));
            *(uint4*)&buf[dst] = v;
        }
    };
    stage(lds[0], kbase0);
    __syncthreads();
    int cur = 0;
    for (int ch = 0; ch < 64; ++ch) {
        int kbase = kbase0 + ch * KB;
        if (ch + 1 < 64) stage(lds[cur ^ 1], kbase + KB);
        // --- QK^T for 2 ntiles of 16 keys ---
        f32x4 acc0 = (f32x4){0.f, 0.f, 0.f, 0.f};
        f32x4 acc1 = (f32x4){0.f, 0.f, 0.f, 0.f};
        const char* base0 = &lds[cur][(c) * 1024];
        const char* base1 = &lds[cur][(16 + c) * 1024];
        const int sw0 = (c & 7) << 4;
#pragma unroll
        for (int ks = 0; ks < 8; ++ks) {
            int off = ((ks * 64 + g * 16) ^ sw0);
            f16x8 bh0 = *(const f16x8*)(base0 + off);
            f16x8 bl0 = *(const f16x8*)(base0 + 512 + off);
            f16x8 bh1 = *(const f16x8*)(base1 + off);
            f16x8 bl1 = *(const f16x8*)(base1 + 512 + off);
            acc0 = __builtin_amdgcn_mfma_f32_16x16x32_f16(ah[ks], bh0, acc0, 0, 0, 0);
            acc0 = __builtin_amdgcn_mfma_f32_16x16x32_f16(al[ks], bh0, acc0, 0, 0, 0);
            acc0 = __builtin_amdgcn_mfma_f32_16x16x32_f16(ah[ks], bl0, acc0, 0, 0, 0);
            acc1 = __builtin_amdgcn_mfma_f32_16x16x32_f16(ah[ks], bh1, acc1, 0, 0, 0);
            acc1 = __builtin_amdgcn_mfma_f32_16x16x32_f16(al[ks], bh1, acc1, 0, 0, 0);
            acc1 = __builtin_amdgcn_mfma_f32_16x16x32_f16(ah[ks], bl1, acc1, 0, 0, 0);
        }
        // --- per-lane online softmax: keys kbase+c, kbase+16+c; rows 4g..4g+3
        int key0 = kbase + c, key1 = kbase + 16 + c;
        float4 va0 = *(const float4*)&vo[key0 * 8];
        float4 vb0 = *(const float4*)&vo[key0 * 8 + 4];
        float4 va1 = *(const float4*)&vo[key1 * 8];
        float4 vb1 = *(const float4*)&vo[key1 * 8 + 4];
        const float v0a[8] = {va0.x, va0.y, va0.z, va0.w, vb0.x, vb0.y, vb0.z, vb0.w};
        const float v1a[8] = {va1.x, va1.y, va1.z, va1.w, vb1.x, vb1.y, vb1.z, vb1.w};
#pragma unroll
        for (int r = 0; r < 4; ++r) {
            float s0 = acc0[r], s1 = acc1[r];
            float cm = fmaxf(s0, s1);
            float mn = fmaxf(m_[r], cm);
            float rs = __expf(m_[r] - mn);
            float p0 = __expf(s0 - mn);
            float p1 = __expf(s1 - mn);
            l_[r] = l_[r] * rs + p0 + p1;
            m_[r] = mn;
#pragma unroll
            for (int e = 0; e < 8; ++e)
                pv[r][e] = fmaf(pv[r][e], rs, fmaf(p0, v0a[e], p1 * v1a[e]));
        }
        __syncthreads();
        cur ^= 1;
    }
    // --- butterfly merge across lanes 0..15 (key-subsets) ---
#pragma unroll
    for (int msk = 1; msk <= 8; msk <<= 1) {
#pragma unroll
        for (int r = 0; r < 4; ++r) {
            float mo = __shfl_xor(m_[r], msk);
            float lo = __shfl_xor(l_[r], msk);
            float mn = fmaxf(m_[r], mo);
            float a = __expf(m_[r] - mn), b = __expf(mo - mn);
            l_[r] = l_[r] * a + lo * b;
#pragma unroll
            for (int e = 0; e < 8; ++e) {
                float po = __shfl_xor(pv[r][e], msk);
                pv[r][e] = pv[r][e] * a + po * b;
            }
            m_[r] = mn;
        }
    }
    if (c == 0) {
#pragma unroll
        for (int r = 0; r < 4; ++r) {
            int n = n0 + w * 16 + g * 4 + r;
            pm[split * NN + n] = m_[r];
            pl[split * NN + n] = l_[r];
#pragma unroll
            for (int e = 0; e < 8; ++e)
                pacc[(size_t)split * NN * 8 + n * 8 + e] = pv[r][e];
        }
    }
}

// ----------------------------------- merge split-K partials -> top2 weights
__global__ __launch_bounds__(256) void k_attn_merge(
    const float* __restrict__ pm, const float* __restrict__ pl,
    const float* __restrict__ pacc, const float* __restrict__ outb,
    float* __restrict__ sparse, int* __restrict__ i1o)
{
    int n = blockIdx.x * 256 + threadIdx.x;
    float mn = -INFINITY;
#pragma unroll
    for (int s = 0; s < ASPLIT; ++s) mn = fmaxf(mn, pm[s * NN + n]);
    float l = 0.f;
    float lg[8];
#pragma unroll
    for (int e = 0; e < 8; ++e) lg[e] = 0.f;
#pragma unroll
    for (int s = 0; s < ASPLIT; ++s) {
        float r = __expf(pm[s * NN + n] - mn);
        l += pl[s * NN + n] * r;
#pragma unroll
        for (int e = 0; e < 8; ++e)
            lg[e] += pacc[(size_t)s * NN * 8 + n * 8 + e] * r;
    }
    float inv = 1.f / l;
#pragma unroll
    for (int e = 0; e < 8; ++e) lg[e] = lg[e] * inv + outb[e];
    int i1 = 0; float v1 = lg[0];
#pragma unroll
    for (int e = 1; e < 8; ++e) if (lg[e] > v1) { v1 = lg[e]; i1 = e; }
    int i2 = -1; float v2 = -INFINITY;
#pragma unroll
    for (int e = 0; e < 8; ++e) if (e != i1 && lg[e] > v2) { v2 = lg[e]; i2 = e; }
    float e2 = __expf(v2 - v1);
    float w1 = 1.f / (1.f + e2);
    float w2 = e2 / (1.f + e2);
#pragma unroll
    for (int e = 0; e < 8; ++e)
        sparse[n * 8 + e] = (e == i1) ? w1 : ((e == i2) ? w2 : 0.f);
    i1o[n] = i1;
}

// ------------------- X = bf16(h + neigh_mean(h)), fp32 z source (layer 1)
__global__ __launch_bounds__(256) void k_agg_f2b(
    const float* __restrict__ src, const int* __restrict__ rowptr,
    const int* __restrict__ colidx, unsigned short* __restrict__ X)
{
    int n = blockIdx.x * 4 + (threadIdx.x >> 6);
    int c4 = (threadIdx.x & 63) * 4;
    int r0 = rowptr[n], r1 = rowptr[n + 1];
    float a0 = 0.f, a1 = 0.f, a2 = 0.f, a3 = 0.f;
    for (int i = r0; i < r1; ++i) {
        int sn = colidx[i];
        float4 v = *(const float4*)&src[(size_t)sn * ZK + c4];
        a0 += v.x; a1 += v.y; a2 += v.z; a3 += v.w;
    }
    int deg = r1 - r0;
    float inv = 1.f / (float)(deg > 1 ? deg : 1);
    float4 self = *(const float4*)&src[(size_t)n * ZK + c4];
    ushort4 o;
    o.x = f2bf(self.x + a0 * inv); o.y = f2bf(self.y + a1 * inv);
    o.z = f2bf(self.z + a2 * inv); o.w = f2bf(self.w + a3 * inv);
    *(ushort4*)&X[(size_t)n * 256 + c4] = o;
}

// ------------------- bf16 source, batched over experts via blockIdx.y
__global__ __launch_bounds__(256) void k_agg_b2b(
    const unsigned short* __restrict__ HeAll, const int* __restrict__ rowptr,
    const int* __restrict__ colidx, unsigned short* __restrict__ XAll)
{
    const unsigned short* He = HeAll + (size_t)blockIdx.y * NN * 256;
    unsigned short* X = XAll + (size_t)blockIdx.y * NN * 256;
    int n = blockIdx.x * 4 + (threadIdx.x >> 6);
    int c4 = (threadIdx.x & 63) * 4;
    int r0 = rowptr[n], r1 = rowptr[n + 1];
    float a0 = 0.f, a1 = 0.f, a2 = 0.f, a3 = 0.f;
    for (int i = r0; i < r1; ++i) {
        int sn = colidx[i];
        ushort4 v = *(const ushort4*)&He[(size_t)sn * 256 + c4];
        a0 += b2f(v.x); a1 += b2f(v.y); a2 += b2f(v.z); a3 += b2f(v.w);
    }
    int deg = r1 - r0;
    float inv = 1.f / (float)(deg > 1 ? deg : 1);
    ushort4 self = *(const ushort4*)&He[(size_t)n * 256 + c4];
    ushort4 o;
    o.x = f2bf(b2f(self.x) + a0 * inv); o.y = f2bf(b2f(self.y) + a1 * inv);
    o.z = f2bf(b2f(self.z) + a2 * inv); o.w = f2bf(b2f(self.w) + a3 * inv);
    *(ushort4*)&X[(size_t)n * 256 + c4] = o;
}

// ------------------------------------------------ out = Ys[0] + Ys[1]
__global__ __launch_bounds__(256) void k_combine2(const float* __restrict__ Ys,
                                                  float* __restrict__ out)
{
    int i = (blockIdx.x * 256 + threadIdx.x) * 4;
    float4 a = *(const float4*)&Ys[i];
    float4 b = *(const float4*)&Ys[(size_t)NN * 256 + i];
    float4 o;
    o.x = a.x + b.x; o.y = a.y + b.y; o.z = a.z + b.z; o.w = a.w + b.w;
    *(float4*)&out[i] = o;
}

// ==========================================================================
extern "C" void kernel_launch(void* const* d_in, const int* in_sizes, int n_in,
                              void* d_out, int out_size, void* d_ws, size_t ws_size,
                              hipStream_t stream)
{
    (void)n_in; (void)out_size;
    const float* x     = (const float*)d_in[0];
    const int*   ei    = (const int*)d_in[1];
    const int*   batch = (const int*)d_in[2];
    const float* encW  = (const float*)d_in[3];
    const float* encb  = (const float*)d_in[4];
    const float* qW    = (const float*)d_in[5];
    const float* qb    = (const float*)d_in[6];
    const float* kW    = (const float*)d_in[7];
    const float* kb    = (const float*)d_in[8];
    const float* vW    = (const float*)d_in[9];
    const float* vb    = (const float*)d_in[10];
    const float* outW  = (const float*)d_in[11];
    const float* outb  = (const float*)d_in[12];
    const float* eWh   = (const float*)d_in[13];
    const float* ebh   = (const float*)d_in[14];
    const float* eWo   = (const float*)d_in[15];
    const float* ebo   = (const float*)d_in[16];
    float* out = (float*)d_out;
    if (in_sizes[0] != NN * 6 || in_sizes[1] != 2 * NE) return;

    char* wsp = (char*)d_ws;
    size_t off = 0;
    auto alloc = [&](size_t bytes) -> void* {
        void* p = wsp + off;
        off += (bytes + 511) & ~(size_t)511;
        return p;
    };
    float* z   = (float*)alloc((size_t)NN * ZK * 4);
    // 16MB block: q/k split-fp16; reused as Ys (2 x NN x 256 fp32) after attn
    _Float16* qh = (_Float16*)alloc((size_t)4 * NN * 256 * 2);
    _Float16* ql = qh + (size_t)NN * 256;
    _Float16* kh = ql + (size_t)NN * 256;
    _Float16* kl = kh + (size_t)NN * 256;
    float* Ys = (float*)qh;
    float* vo     = (float*)alloc((size_t)NN * 8 * 4);
    float* sparse = (float*)alloc((size_t)NN * 8 * 4);
    int*   i1buf  = (int*)alloc((size_t)NN * 4);
    unsigned short* Xball = (unsigned short*)alloc((size_t)8 * NN * 256 * 2);
    unsigned short* Heb   = (unsigned short*)alloc((size_t)8 * NN * 256 * 2);
    unsigned short* Bth   = (unsigned short*)alloc((size_t)16 * 65536 * 2);
    unsigned short* Bto   = (unsigned short*)alloc((size_t)8 * 65536 * 2);
    float* Wq   = (float*)alloc((size_t)ZK * 256 * 4);
    float* Wk   = (float*)alloc((size_t)ZK * 256 * 4);
    float* Wvo  = (float*)alloc((size_t)ZK * 8 * 4);
    float* bvo  = (float*)alloc(8 * 4);
    float* pm   = (float*)alloc((size_t)ASPLIT * NN * 4);
    float* plb  = (float*)alloc((size_t)ASPLIT * NN * 4);
    float* pacc = (float*)alloc((size_t)ASPLIT * NN * 8 * 4);
    int* ints   = (int*)alloc((size_t)(NG + NG + NN + NN) * 4);
    int* ncnt = ints, *ecnt = ints + NG, *indeg = ecnt + NG, *cursor = indeg + NN;
    int* rowptr = (int*)alloc((size_t)(NN + 1) * 4);
    int* colidx = (int*)alloc((size_t)NE * 4);
    if (off > ws_size) return;

    hipMemsetAsync(ints, 0, (size_t)(NG + NG + NN + NN) * 4, stream);
    k_counts<<<(NE + 255) / 256, 256, 0, stream>>>(ei, batch, ncnt, ecnt, indeg);
    k_prep_qk<<<ZK, 256, 0, stream>>>(qW, kW, Wq, Wk);
    k_prep_vo<<<(ZK * 8 + 8 + 255) / 256, 256, 0, stream>>>(vW, vb, outW, Wvo, bvo);
    k_prep_w<<<(24 * 65536) / 256, 256, 0, stream>>>(eWh, eWo, Bth, Bto);
    k_encoder<<<NN, 256, 0, stream>>>(x, encW, encb, batch, ncnt, ecnt, z);
    k_scan<<<1, 256, 0, stream>>>(indeg, rowptr);
    k_fill<<<(NE + 255) / 256, 256, 0, stream>>>(ei, rowptr, cursor, colidx);

    float scale = 1.f / sqrtf(258.f);
    dim3 g1(256 / 64, NN / 128, 1);
    k_gemm_qk<<<g1, 256, 0, stream>>>(z, Wq, qb, qh, ql, scale, ZK);
    k_gemm_qk<<<g1, 256, 0, stream>>>(z, Wk, kb, kh, kl, 1.0f, ZK);
    k_vo<<<NN / 4, 256, 0, stream>>>(z, Wvo, bvo, vo);

    k_attn_mfma<<<(NN / QB) * ASPLIT, 256, 0, stream>>>(qh, ql, kh, kl, vo, pm, plb, pacc);
    k_attn_merge<<<NN / 256, 256, 0, stream>>>(pm, plb, pacc, outb, sparse, i1buf);

    // ---- experts: 3 batched agg + 3 batched MFMA GEMMs + combine ----
    k_agg_f2b<<<NN / 4, 256, 0, stream>>>(z, rowptr, colidx, Xball);  // slot 0
    dim3 gb8(256 / 64, NN / 128, 8);
    dim3 ga8(NN / 4, 8, 1);
    // layer 1: shared A (Xball slot 0)
    k_gemm_bf<<<gb8, 256, 0, stream>>>(Xball, Bth, ebh, Heb, nullptr, nullptr, nullptr,
                                       0, (long long)2 * 65536, (long long)NN * 256,
                                       2 * 256, 0);
    // layer 2
    k_agg_b2b<<<ga8, 256, 0, stream>>>(Heb, rowptr, colidx, Xball);
    k_gemm_bf<<<gb8, 256, 0, stream>>>(Xball, Bth + 65536, ebh + 256, Heb,
                                       nullptr, nullptr, nullptr,
                                       (long long)NN * 256, (long long)2 * 65536,
                                       (long long)NN * 256, 2 * 256, 0);
    // layer 3 -> top-2 slot buffers
    k_agg_b2b<<<ga8, 256, 0, stream>>>(Heb, rowptr, colidx, Xball);
    k_gemm_bf<<<gb8, 256, 0, stream>>>(Xball, Bto, ebo, nullptr, Ys, sparse, i1buf,
                                       (long long)NN * 256, (long long)65536,
                                       0, 256, 1);
    k_combine2<<<(NN * 256 / 4) / 256, 256, 0, stream>>>(Ys, out);
}

// Round 4
// 535.230 us; speedup vs baseline: 3.4987x; 1.4142x over previous
//
#include <hip/hip_runtime.h>
#include <math.h>

#define NN 8192      // nodes
#define NE 131072    // edges
#define ZK 288       // padded z width (258 -> 288, multiple of 32)
#define NG 64        // graphs
#define ASPLIT 4     // attention split-K
#define QB 64        // q-rows per attention block
#define KB 32        // keys per attention chunk

typedef __attribute__((ext_vector_type(8))) short bf16x8;
typedef __attribute__((ext_vector_type(4))) float f32x4;
typedef __attribute__((ext_vector_type(8))) _Float16 f16x8;
typedef __attribute__((ext_vector_type(4))) _Float16 f16x4;

static __device__ __forceinline__ unsigned short f2bf(float f) {
    unsigned u = __float_as_uint(f);
    unsigned r = (u + 0x7FFFu + ((u >> 16) & 1u)) >> 16;   // RNE
    return (unsigned short)r;
}
static __device__ __forceinline__ float b2f(unsigned short h) {
    return __uint_as_float(((unsigned)h) << 16);
}

// ------------------------- counts via per-block LDS histograms (G12)
// 64 blocks; block b: edges [b*2048,(b+1)*2048), nodes [b*128,(b+1)*128)
__global__ __launch_bounds__(256) void k_counts(const int* __restrict__ ei,
    const int* __restrict__ batch, int* ncnt, int* ecnt, int* indeg)
{
    __shared__ int he[NG], hn[NG];
    const int t = threadIdx.x, b = blockIdx.x;
    if (t < NG) { he[t] = 0; hn[t] = 0; }
    __syncthreads();
    const int e0 = b * (NE / 64);
#pragma unroll
    for (int i = 0; i < (NE / 64) / 256; ++i) {
        int idx = e0 + i * 256 + t;
        int src = ei[idx], dst = ei[NE + idx];
        atomicAdd(&he[batch[src]], 1);
        atomicAdd(&indeg[dst], 1);          // spread over 8192 addrs: cheap
    }
    if (t < 128) atomicAdd(&hn[batch[b * 128 + t]], 1);
    __syncthreads();
    if (t < NG) {
        if (he[t]) atomicAdd(&ecnt[t], he[t]);
        if (hn[t]) atomicAdd(&ncnt[t], hn[t]);
    }
}

// ---------------- encoder + size feats -> z (fp32, ZK) and zb (bf16, 256)
__global__ __launch_bounds__(256) void k_encoder(const float* __restrict__ x,
    const float* __restrict__ encW, const float* __restrict__ encb,
    const int* __restrict__ batch, const int* __restrict__ ncnt,
    const int* __restrict__ ecnt, float* __restrict__ z,
    unsigned short* __restrict__ zb)
{
    int n = blockIdx.x, c = threadIdx.x;
    __shared__ float xr[8];
    if (c < 6) xr[c] = x[n * 6 + c];
    __syncthreads();
    float a = encb[c];
#pragma unroll
    for (int i = 0; i < 6; ++i) a = fmaf(xr[i], encW[i * 256 + c], a);
    float h = fmaxf(a, 0.f);
    z[n * ZK + c] = h;
    zb[n * 256 + c] = f2bf(h);
    if (c == 0) {
        int g = batch[n];
        z[n * ZK + 256] = log1pf((float)ncnt[g]);
        z[n * ZK + 257] = log1pf((float)ecnt[g]);
    }
    if (c >= 2 && c < 32) z[n * ZK + 256 + c] = 0.f;  // zero pad 258..287
}

// ---------------------------------------------------------------- CSR build
__global__ __launch_bounds__(256) void k_scan(const int* __restrict__ indeg,
                                              int* __restrict__ rowptr)
{
    __shared__ int part[256];
    int t = threadIdx.x;
    int base = t * 32, s = 0;
    for (int i = 0; i < 32; ++i) s += indeg[base + i];
    part[t] = s;
    __syncthreads();
    if (t == 0) {
        int run = 0;
        for (int i = 0; i < 256; ++i) { int v = part[i]; part[i] = run; run += v; }
        rowptr[NN] = run;
    }
    __syncthreads();
    int run = part[t];
    for (int i = 0; i < 32; ++i) { rowptr[base + i] = run; run += indeg[base + i]; }
}

__global__ __launch_bounds__(256) void k_fill(const int* __restrict__ ei,
    const int* __restrict__ rowptr, int* __restrict__ cursor, int* __restrict__ colidx)
{
    int tid = blockIdx.x * 256 + threadIdx.x;
    if (tid >= NE) return;
    int dst = ei[NE + tid];
    int pos = atomicAdd(&cursor[dst], 1);
    colidx[rowptr[dst] + pos] = ei[tid];
}

// ------------------------------------------------------- weight preparation
__global__ __launch_bounds__(256) void k_prep_qk(const float* __restrict__ qW,
    const float* __restrict__ kW, float* __restrict__ Wq, float* __restrict__ Wk)
{
    int idx = blockIdx.x * 256 + threadIdx.x;  // < ZK*256 exactly
    int r = idx >> 8, c = idx & 255;
    Wq[idx] = (r < 258) ? qW[r * 256 + c] : 0.f;
    Wk[idx] = (r < 258) ? kW[r * 256 + c] : 0.f;
}

// W_vo = v_W @ out_W (padded to ZK rows), bvo = v_b @ out_W
__global__ __launch_bounds__(256) void k_prep_vo(const float* __restrict__ vW,
    const float* __restrict__ vb, const float* __restrict__ outW,
    float* __restrict__ Wvo, float* __restrict__ bvo)
{
    int idx = blockIdx.x * 256 + threadIdx.x;
    if (idx < ZK * 8) {
        int r = idx >> 3, e = idx & 7;
        float s = 0.f;
        if (r < 258)
            for (int c = 0; c < 256; ++c) s = fmaf(vW[r * 256 + c], outW[c * 8 + e], s);
        Wvo[idx] = s;
    } else if (idx < ZK * 8 + 8) {
        int e = idx - ZK * 8;
        float s = 0.f;
        for (int c = 0; c < 256; ++c) s = fmaf(vb[c], outW[c * 8 + e], s);
        bvo[e] = s;
    }
}

// expert weights -> bf16, transposed to [out][in] so B-frags load contiguous
__global__ __launch_bounds__(256) void k_prep_w(const float* __restrict__ eWh,
    const float* __restrict__ eWo, unsigned short* __restrict__ Bth,
    unsigned short* __restrict__ Bto)
{
    int id = blockIdx.x * 256 + threadIdx.x;
    if (id < 16 * 65536) {
        int h = id & 255, kcol = (id >> 8) & 255, m = id >> 16;  // m = e*2+l
        Bth[id] = f2bf(eWh[((size_t)m * 256 + h) * 256 + kcol]);
    } else if (id < 24 * 65536) {
        int j = id - 16 * 65536;
        int h = j & 255, o = (j >> 8) & 255, e = j >> 16;
        Bto[j] = f2bf(eWo[((size_t)e * 256 + h) * 256 + o]);
    }
}

// ---------------- fp32 GEMM writing split-fp16 (hi,lo); z-batched over q/k
__global__ __launch_bounds__(256) void k_gemm_qk(
    const float* __restrict__ A,
    const float* __restrict__ Wq, const float* __restrict__ Wk,
    const float* __restrict__ qb, const float* __restrict__ kb,
    _Float16* __restrict__ qh, _Float16* __restrict__ ql,
    _Float16* __restrict__ kh, _Float16* __restrict__ kl,
    float scale, int K)
{
    const float* B    = blockIdx.z ? Wk : Wq;
    const float* bias = blockIdx.z ? kb : qb;
    _Float16* Ch = blockIdx.z ? kh : qh;
    _Float16* Cl = blockIdx.z ? kl : ql;
    const float scl = blockIdx.z ? 1.0f : scale;
    __shared__ float As[32][132];
    __shared__ float Bs[32][68];
    int t = threadIdx.x;
    int m0 = blockIdx.y * 128, n0 = blockIdx.x * 64;
    int tr = t & 15, tc = t >> 4;
    float acc[8][4];
#pragma unroll
    for (int i = 0; i < 8; ++i)
#pragma unroll
        for (int j = 0; j < 4; ++j) acc[i][j] = 0.f;

    for (int k0 = 0; k0 < K; k0 += 32) {
#pragma unroll
        for (int i = 0; i < 4; ++i) {
            int f = t + 256 * i;
            int kc = f & 7, row = f >> 3;
            float4 v = *(const float4*)&A[(size_t)(m0 + row) * ZK + k0 + 4 * kc];
            As[4 * kc + 0][row] = v.x; As[4 * kc + 1][row] = v.y;
            As[4 * kc + 2][row] = v.z; As[4 * kc + 3][row] = v.w;
        }
#pragma unroll
        for (int i = 0; i < 2; ++i) {
            int f = t + 256 * i;
            int nc = f & 15, krow = f >> 4;
            *(float4*)&Bs[krow][4 * nc] =
                *(const float4*)&B[(size_t)(k0 + krow) * 256 + n0 + 4 * nc];
        }
        __syncthreads();
#pragma unroll
        for (int kk = 0; kk < 32; ++kk) {
            float4 a0 = *(const float4*)&As[kk][4 * tr];
            float4 a1 = *(const float4*)&As[kk][64 + 4 * tr];
            float4 b  = *(const float4*)&Bs[kk][4 * tc];
            const float av0[4] = {a0.x, a0.y, a0.z, a0.w};
            const float av1[4] = {a1.x, a1.y, a1.z, a1.w};
            const float bv[4]  = {b.x, b.y, b.z, b.w};
#pragma unroll
            for (int i = 0; i < 4; ++i)
#pragma unroll
                for (int j = 0; j < 4; ++j) {
                    acc[i][j]     = fmaf(av0[i], bv[j], acc[i][j]);
                    acc[4 + i][j] = fmaf(av1[i], bv[j], acc[4 + i][j]);
                }
        }
        __syncthreads();
    }
    float4 bi = *(const float4*)&bias[n0 + 4 * tc];
    const float bb[4] = {bi.x, bi.y, bi.z, bi.w};
#pragma unroll
    for (int h = 0; h < 2; ++h)
#pragma unroll
        for (int i = 0; i < 4; ++i) {
            int m = m0 + h * 64 + 4 * tr + i;
            f16x4 vh, vl;
#pragma unroll
            for (int j = 0; j < 4; ++j) {
                float v = (acc[h * 4 + i][j] + bb[j]) * scl;
                _Float16 hi = (_Float16)v;
                vh[j] = hi;
                vl[j] = (_Float16)(v - (float)hi);
            }
            *(f16x4*)&Ch[(size_t)m * 256 + n0 + 4 * tc] = vh;
            *(f16x4*)&Cl[(size_t)m * 256 + n0 + 4 * tc] = vl;
        }
}

// ----------------------------------------------------- bf16 MFMA GEMM
// C = act(A[M,256] @ B^T + bias); BM=128 BN=64, 4 waves 2x2, 16x16x32.
// mode 0: relu -> bf16 Cb.  mode 1: Ys[slot] = w*(acc+bias) (top-2 slots).
__global__ __launch_bounds__(256) void k_gemm_bf(
    const unsigned short* __restrict__ A,
    const unsigned short* __restrict__ Bt,
    const float* __restrict__ bias,
    unsigned short* __restrict__ Cb,
    float* __restrict__ Ys,
    const float* __restrict__ sparse,
    const int* __restrict__ i1,
    long long aStrideZ, long long btStrideZ, long long cStrideZ, int biasStrideZ,
    int mode)
{
    const int ez = blockIdx.z;
    A    += (size_t)ez * aStrideZ;
    Bt   += (size_t)ez * btStrideZ;
    bias += (size_t)ez * biasStrideZ;
    if (mode == 0) Cb += (size_t)ez * cStrideZ;
    __shared__ unsigned short As[128][40];
    __shared__ unsigned short Bs[64][40];
    const int t = threadIdx.x;
    const int m0 = blockIdx.y * 128, n0 = blockIdx.x * 64;
    const int wid = t >> 6, lane = t & 63;
    const int wr = wid >> 1, wc = wid & 1;
    const int lr = lane & 15, lg = lane >> 4;
    f32x4 acc[4][2];
#pragma unroll
    for (int mf = 0; mf < 4; ++mf)
#pragma unroll
        for (int nf = 0; nf < 2; ++nf) acc[mf][nf] = (f32x4){0.f, 0.f, 0.f, 0.f};

    const int rA0 = t >> 2, cA0 = t & 3;
    for (int k0 = 0; k0 < 256; k0 += 32) {
        uint4 va = *(const uint4*)&A[(size_t)(m0 + rA0) * 256 + k0 + 8 * cA0];
        uint4 vb = *(const uint4*)&A[(size_t)(m0 + 64 + rA0) * 256 + k0 + 8 * cA0];
        uint4 vB = *(const uint4*)&Bt[(size_t)(n0 + rA0) * 256 + k0 + 8 * cA0];
        *(uint4*)&As[rA0][8 * cA0] = va;
        *(uint4*)&As[64 + rA0][8 * cA0] = vb;
        *(uint4*)&Bs[rA0][8 * cA0] = vB;
        __syncthreads();
        bf16x8 a[4], b[2];
#pragma unroll
        for (int mf = 0; mf < 4; ++mf)
            a[mf] = *(const bf16x8*)&As[wr * 64 + mf * 16 + lr][8 * lg];
#pragma unroll
        for (int nf = 0; nf < 2; ++nf)
            b[nf] = *(const bf16x8*)&Bs[wc * 32 + nf * 16 + lr][8 * lg];
#pragma unroll
        for (int mf = 0; mf < 4; ++mf)
#pragma unroll
            for (int nf = 0; nf < 2; ++nf)
                acc[mf][nf] = __builtin_amdgcn_mfma_f32_16x16x32_bf16(
                    a[mf], b[nf], acc[mf][nf], 0, 0, 0);
        __syncthreads();
    }
    if (mode == 0) {
#pragma unroll
        for (int mf = 0; mf < 4; ++mf)
#pragma unroll
            for (int reg = 0; reg < 4; ++reg) {
                int m = m0 + wr * 64 + mf * 16 + lg * 4 + reg;
#pragma unroll
                for (int nf = 0; nf < 2; ++nf) {
                    int c = n0 + wc * 32 + nf * 16 + lr;
                    float v = acc[mf][nf][reg] + bias[c];
                    Cb[(size_t)m * 256 + c] = f2bf(fmaxf(v, 0.f));
                }
            }
    } else {
#pragma unroll
        for (int mf = 0; mf < 4; ++mf)
#pragma unroll
            for (int reg = 0; reg < 4; ++reg) {
                int m = m0 + wr * 64 + mf * 16 + lg * 4 + reg;
                float w = sparse[m * 8 + ez];
                if (w != 0.f) {
                    int slot = (ez == i1[m]) ? 0 : 1;
                    float* dst = Ys + (size_t)slot * NN * 256 + (size_t)m * 256;
#pragma unroll
                    for (int nf = 0; nf < 2; ++nf) {
                        int c = n0 + wc * 32 + nf * 16 + lr;
                        dst[c] = w * (acc[mf][nf][reg] + bias[c]);
                    }
                }
            }
    }
}

// ------------------------------------------------------------- vo = z @ Wvo
__global__ __launch_bounds__(256) void k_vo(const float* __restrict__ z,
    const float* __restrict__ Wvo, const float* __restrict__ bvo,
    float* __restrict__ vo)
{
    int n = blockIdx.x * 4 + (threadIdx.x >> 6);
    int lane = threadIdx.x & 63;
    float p[8];
#pragma unroll
    for (int e = 0; e < 8; ++e) p[e] = 0.f;
    for (int kk = lane; kk < ZK; kk += 64) {
        float zv = z[(size_t)n * ZK + kk];
        float4 w0 = *(const float4*)&Wvo[kk * 8];
        float4 w1 = *(const float4*)&Wvo[kk * 8 + 4];
        p[0] = fmaf(zv, w0.x, p[0]); p[1] = fmaf(zv, w0.y, p[1]);
        p[2] = fmaf(zv, w0.z, p[2]); p[3] = fmaf(zv, w0.w, p[3]);
        p[4] = fmaf(zv, w1.x, p[4]); p[5] = fmaf(zv, w1.y, p[5]);
        p[6] = fmaf(zv, w1.z, p[6]); p[7] = fmaf(zv, w1.w, p[7]);
    }
#pragma unroll
    for (int msk = 1; msk <= 32; msk <<= 1)
#pragma unroll
        for (int e = 0; e < 8; ++e) p[e] += __shfl_xor(p[e], msk);
    if (lane == 0) {
#pragma unroll
        for (int e = 0; e < 8; ++e) vo[n * 8 + e] = p[e] + bvo[e];
    }
}

// ---------------------------------------- split-fp16 MFMA flash attention
// 64 q-rows/block (4 waves x 16 rows), split-K=4, K staged in swizzled LDS.
// s = qh*kh + qh*kl + ql*kh (fp32 MFMA accum). Per-lane private online softmax.
__global__ __launch_bounds__(256, 2) void k_attn_mfma(
    const _Float16* __restrict__ qh, const _Float16* __restrict__ ql,
    const _Float16* __restrict__ kh, const _Float16* __restrict__ kl,
    const float* __restrict__ vo, float* __restrict__ pm,
    float* __restrict__ pl, float* __restrict__ pacc)
{
    __shared__ char lds[2][KB * 1024];   // per key: 512B hi | 512B lo, swizzled
    const int bid = blockIdx.x;
    const int xcd = bid & 7;
    const int split = xcd >> 1;                       // XCD pair owns a split
    const int qblk = ((bid >> 3) << 1) + (xcd & 1);   // 0..127
    const int n0 = qblk * QB;
    const int t = threadIdx.x, w = t >> 6, lane = t & 63;
    const int g = lane >> 4, c = lane & 15;
    const int row = n0 + w * 16 + c;

    // Q A-fragments, persistent in registers
    f16x8 ah[8], al[8];
#pragma unroll
    for (int ks = 0; ks < 8; ++ks) {
        ah[ks] = *(const f16x8*)&qh[(size_t)row * 256 + ks * 32 + g * 8];
        al[ks] = *(const f16x8*)&ql[(size_t)row * 256 + ks * 32 + g * 8];
    }
    float m_[4], l_[4], pv[4][8];
#pragma unroll
    for (int r = 0; r < 4; ++r) {
        m_[r] = -INFINITY; l_[r] = 0.f;
#pragma unroll
        for (int e = 0; e < 8; ++e) pv[r][e] = 0.f;
    }
    const int kbase0 = split * 2048;

    // stage chunk: 32 keys x (512B hi + 512B lo), 16B-unit XOR swizzle by key
    auto stage = [&](char* buf, int kb) {
#pragma unroll
        for (int i = 0; i < 8; ++i) {
            int u = i * 256 + t;
            int key = u >> 6, ur = u & 63;
            int half = ur >> 5, c16 = ur & 31;
            const _Float16* src = half ? kl : kh;
            uint4 v = *(const uint4*)&src[(size_t)(kb + key) * 256 + c16 * 8];
            int dst = key * 1024 + half * 512 + ((c16 * 16) ^ ((key & 7) << 4));
            *(uint4*)&buf[dst] = v;
        }
    };
    stage(lds[0], kbase0);
    __syncthreads();
    int cur = 0;
    for (int ch = 0; ch < 64; ++ch) {
        int kbase = kbase0 + ch * KB;
        if (ch + 1 < 64) stage(lds[cur ^ 1], kbase + KB);
        // --- QK^T for 2 ntiles of 16 keys ---
        f32x4 acc0 = (f32x4){0.f, 0.f, 0.f, 0.f};
        f32x4 acc1 = (f32x4){0.f, 0.f, 0.f, 0.f};
        const char* base0 = &lds[cur][(c) * 1024];
        const char* base1 = &lds[cur][(16 + c) * 1024];
        const int sw0 = (c & 7) << 4;
#pragma unroll
        for (int ks = 0; ks < 8; ++ks) {
            int off = ((ks * 64 + g * 16) ^ sw0);
            f16x8 bh0 = *(const f16x8*)(base0 + off);
            f16x8 bl0 = *(const f16x8*)(base0 + 512 + off);
            f16x8 bh1 = *(const f16x8*)(base1 + off);
            f16x8 bl1 = *(const f16x8*)(base1 + 512 + off);
            acc0 = __builtin_amdgcn_mfma_f32_16x16x32_f16(ah[ks], bh0, acc0, 0, 0, 0);
            acc0 = __builtin_amdgcn_mfma_f32_16x16x32_f16(al[ks], bh0, acc0, 0, 0, 0);
            acc0 = __builtin_amdgcn_mfma_f32_16x16x32_f16(ah[ks], bl0, acc0, 0, 0, 0);
            acc1 = __builtin_amdgcn_mfma_f32_16x16x32_f16(ah[ks], bh1, acc1, 0, 0, 0);
            acc1 = __builtin_amdgcn_mfma_f32_16x16x32_f16(al[ks], bh1, acc1, 0, 0, 0);
            acc1 = __builtin_amdgcn_mfma_f32_16x16x32_f16(ah[ks], bl1, acc1, 0, 0, 0);
        }
        // --- per-lane online softmax: keys kbase+c, kbase+16+c; rows 4g..4g+3
        int key0 = kbase + c, key1 = kbase + 16 + c;
        float4 va0 = *(const float4*)&vo[key0 * 8];
        float4 vb0 = *(const float4*)&vo[key0 * 8 + 4];
        float4 va1 = *(const float4*)&vo[key1 * 8];
        float4 vb1 = *(const float4*)&vo[key1 * 8 + 4];
        const float v0a[8] = {va0.x, va0.y, va0.z, va0.w, vb0.x, vb0.y, vb0.z, vb0.w};
        const float v1a[8] = {va1.x, va1.y, va1.z, va1.w, vb1.x, vb1.y, vb1.z, vb1.w};
#pragma unroll
        for (int r = 0; r < 4; ++r) {
            float s0 = acc0[r], s1 = acc1[r];
            float cm = fmaxf(s0, s1);
            float mn = fmaxf(m_[r], cm);
            float rs = __expf(m_[r] - mn);
            float p0 = __expf(s0 - mn);
            float p1 = __expf(s1 - mn);
            l_[r] = l_[r] * rs + p0 + p1;
            m_[r] = mn;
#pragma unroll
            for (int e = 0; e < 8; ++e)
                pv[r][e] = fmaf(pv[r][e], rs, fmaf(p0, v0a[e], p1 * v1a[e]));
        }
        __syncthreads();
        cur ^= 1;
    }
    // --- butterfly merge across lanes 0..15 (key-subsets) ---
#pragma unroll
    for (int msk = 1; msk <= 8; msk <<= 1) {
#pragma unroll
        for (int r = 0; r < 4; ++r) {
            float mo = __shfl_xor(m_[r], msk);
            float lo = __shfl_xor(l_[r], msk);
            float mn = fmaxf(m_[r], mo);
            float a = __expf(m_[r] - mn), b = __expf(mo - mn);
            l_[r] = l_[r] * a + lo * b;
#pragma unroll
            for (int e = 0; e < 8; ++e) {
                float po = __shfl_xor(pv[r][e], msk);
                pv[r][e] = pv[r][e] * a + po * b;
            }
            m_[r] = mn;
        }
    }
    if (c == 0) {
#pragma unroll
        for (int r = 0; r < 4; ++r) {
            int n = n0 + w * 16 + g * 4 + r;
            pm[split * NN + n] = m_[r];
            pl[split * NN + n] = l_[r];
#pragma unroll
            for (int e = 0; e < 8; ++e)
                pacc[(size_t)split * NN * 8 + n * 8 + e] = pv[r][e];
        }
    }
}

// ----------------------------------- merge split-K partials -> top2 weights
__global__ __launch_bounds__(256) void k_attn_merge(
    const float* __restrict__ pm, const float* __restrict__ pl,
    const float* __restrict__ pacc, const float* __restrict__ outb,
    float* __restrict__ sparse, int* __restrict__ i1o)
{
    int n = blockIdx.x * 256 + threadIdx.x;
    float mn = -INFINITY;
#pragma unroll
    for (int s = 0; s < ASPLIT; ++s) mn = fmaxf(mn, pm[s * NN + n]);
    float l = 0.f;
    float lg[8];
#pragma unroll
    for (int e = 0; e < 8; ++e) lg[e] = 0.f;
#pragma unroll
    for (int s = 0; s < ASPLIT; ++s) {
        float r = __expf(pm[s * NN + n] - mn);
        l += pl[s * NN + n] * r;
#pragma unroll
        for (int e = 0; e < 8; ++e)
            lg[e] += pacc[(size_t)s * NN * 8 + n * 8 + e] * r;
    }
    float inv = 1.f / l;
#pragma unroll
    for (int e = 0; e < 8; ++e) lg[e] = lg[e] * inv + outb[e];
    int i1 = 0; float v1 = lg[0];
#pragma unroll
    for (int e = 1; e < 8; ++e) if (lg[e] > v1) { v1 = lg[e]; i1 = e; }
    int i2 = -1; float v2 = -INFINITY;
#pragma unroll
    for (int e = 0; e < 8; ++e) if (e != i1 && lg[e] > v2) { v2 = lg[e]; i2 = e; }
    float e2 = __expf(v2 - v1);
    float w1 = 1.f / (1.f + e2);
    float w2 = e2 / (1.f + e2);
#pragma unroll
    for (int e = 0; e < 8; ++e)
        sparse[n * 8 + e] = (e == i1) ? w1 : ((e == i2) ? w2 : 0.f);
    i1o[n] = i1;
}

// ------------------- bf16 gather-mean: X = bf16(src + neigh_mean(src))
// batched over blockIdx.y experts (src/dst stride NN*256)
__global__ __launch_bounds__(256) void k_agg_b2b(
    const unsigned short* __restrict__ HeAll, const int* __restrict__ rowptr,
    const int* __restrict__ colidx, unsigned short* __restrict__ XAll)
{
    const unsigned short* He = HeAll + (size_t)blockIdx.y * NN * 256;
    unsigned short* X = XAll + (size_t)blockIdx.y * NN * 256;
    int n = blockIdx.x * 4 + (threadIdx.x >> 6);
    int c4 = (threadIdx.x & 63) * 4;
    int r0 = rowptr[n], r1 = rowptr[n + 1];
    float a0 = 0.f, a1 = 0.f, a2 = 0.f, a3 = 0.f;
    for (int i = r0; i < r1; ++i) {
        int sn = colidx[i];
        ushort4 v = *(const ushort4*)&He[(size_t)sn * 256 + c4];
        a0 += b2f(v.x); a1 += b2f(v.y); a2 += b2f(v.z); a3 += b2f(v.w);
    }
    int deg = r1 - r0;
    float inv = 1.f / (float)(deg > 1 ? deg : 1);
    ushort4 self = *(const ushort4*)&He[(size_t)n * 256 + c4];
    ushort4 o;
    o.x = f2bf(b2f(self.x) + a0 * inv); o.y = f2bf(b2f(self.y) + a1 * inv);
    o.z = f2bf(b2f(self.z) + a2 * inv); o.w = f2bf(b2f(self.w) + a3 * inv);
    *(ushort4*)&X[(size_t)n * 256 + c4] = o;
}

// ------------------------------------------------ out = Ys[0] + Ys[1]
__global__ __launch_bounds__(256) void k_combine2(const float* __restrict__ Ys,
                                                  float* __restrict__ out)
{
    int i = (blockIdx.x * 256 + threadIdx.x) * 4;
    float4 a = *(const float4*)&Ys[i];
    float4 b = *(const float4*)&Ys[(size_t)NN * 256 + i];
    float4 o;
    o.x = a.x + b.x; o.y = a.y + b.y; o.z = a.z + b.z; o.w = a.w + b.w;
    *(float4*)&out[i] = o;
}

// ==========================================================================
extern "C" void kernel_launch(void* const* d_in, const int* in_sizes, int n_in,
                              void* d_out, int out_size, void* d_ws, size_t ws_size,
                              hipStream_t stream)
{
    (void)n_in; (void)out_size;
    const float* x     = (const float*)d_in[0];
    const int*   ei    = (const int*)d_in[1];
    const int*   batch = (const int*)d_in[2];
    const float* encW  = (const float*)d_in[3];
    const float* encb  = (const float*)d_in[4];
    const float* qW    = (const float*)d_in[5];
    const float* qb    = (const float*)d_in[6];
    const float* kW    = (const float*)d_in[7];
    const float* kb    = (const float*)d_in[8];
    const float* vW    = (const float*)d_in[9];
    const float* vb    = (const float*)d_in[10];
    const float* outW  = (const float*)d_in[11];
    const float* outb  = (const float*)d_in[12];
    const float* eWh   = (const float*)d_in[13];
    const float* ebh   = (const float*)d_in[14];
    const float* eWo   = (const float*)d_in[15];
    const float* ebo   = (const float*)d_in[16];
    float* out = (float*)d_out;
    if (in_sizes[0] != NN * 6 || in_sizes[1] != 2 * NE) return;

    char* wsp = (char*)d_ws;
    size_t off = 0;
    auto alloc = [&](size_t bytes) -> void* {
        void* p = wsp + off;
        off += (bytes + 511) & ~(size_t)511;
        return p;
    };
    float* z   = (float*)alloc((size_t)NN * ZK * 4);
    unsigned short* zb = (unsigned short*)alloc((size_t)NN * 256 * 2);
    // 16MB block: q/k split-fp16; reused as Ys (2 x NN x 256 fp32) after attn
    _Float16* qh = (_Float16*)alloc((size_t)4 * NN * 256 * 2);
    _Float16* ql = qh + (size_t)NN * 256;
    _Float16* kh = ql + (size_t)NN * 256;
    _Float16* kl = kh + (size_t)NN * 256;
    float* Ys = (float*)qh;
    float* vo     = (float*)alloc((size_t)NN * 8 * 4);
    float* sparse = (float*)alloc((size_t)NN * 8 * 4);
    int*   i1buf  = (int*)alloc((size_t)NN * 4);
    unsigned short* Xball = (unsigned short*)alloc((size_t)8 * NN * 256 * 2);
    unsigned short* Heb   = (unsigned short*)alloc((size_t)8 * NN * 256 * 2);
    unsigned short* Bth   = (unsigned short*)alloc((size_t)16 * 65536 * 2);
    unsigned short* Bto   = (unsigned short*)alloc((size_t)8 * 65536 * 2);
    float* Wq   = (float*)alloc((size_t)ZK * 256 * 4);
    float* Wk   = (float*)alloc((size_t)ZK * 256 * 4);
    float* Wvo  = (float*)alloc((size_t)ZK * 8 * 4);
    float* bvo  = (float*)alloc(8 * 4);
    float* pm   = (float*)alloc((size_t)ASPLIT * NN * 4);
    float* plb  = (float*)alloc((size_t)ASPLIT * NN * 4);
    float* pacc = (float*)alloc((size_t)ASPLIT * NN * 8 * 4);
    int* ints   = (int*)alloc((size_t)(NG + NG + NN + NN) * 4);
    int* ncnt = ints, *ecnt = ints + NG, *indeg = ecnt + NG, *cursor = indeg + NN;
    int* rowptr = (int*)alloc((size_t)(NN + 1) * 4);
    int* colidx = (int*)alloc((size_t)NE * 4);
    if (off > ws_size) return;

    hipMemsetAsync(ints, 0, (size_t)(NG + NG + NN + NN) * 4, stream);
    k_counts<<<64, 256, 0, stream>>>(ei, batch, ncnt, ecnt, indeg);
    k_prep_qk<<<ZK, 256, 0, stream>>>(qW, kW, Wq, Wk);
    k_prep_vo<<<(ZK * 8 + 8 + 255) / 256, 256, 0, stream>>>(vW, vb, outW, Wvo, bvo);
    k_prep_w<<<(24 * 65536) / 256, 256, 0, stream>>>(eWh, eWo, Bth, Bto);
    k_encoder<<<NN, 256, 0, stream>>>(x, encW, encb, batch, ncnt, ecnt, z, zb);
    k_scan<<<1, 256, 0, stream>>>(indeg, rowptr);
    k_fill<<<(NE + 255) / 256, 256, 0, stream>>>(ei, rowptr, cursor, colidx);

    float scale = 1.f / sqrtf(258.f);
    dim3 gqk(256 / 64, NN / 128, 2);
    k_gemm_qk<<<gqk, 256, 0, stream>>>(z, Wq, Wk, qb, kb, qh, ql, kh, kl, scale, ZK);
    k_vo<<<NN / 4, 256, 0, stream>>>(z, Wvo, bvo, vo);

    k_attn_mfma<<<(NN / QB) * ASPLIT, 256, 0, stream>>>(qh, ql, kh, kl, vo, pm, plb, pacc);
    k_attn_merge<<<NN / 256, 256, 0, stream>>>(pm, plb, pacc, outb, sparse, i1buf);

    // ---- experts: 3 batched agg + 3 batched MFMA GEMMs + combine ----
    dim3 ga1(NN / 4, 1, 1);
    k_agg_b2b<<<ga1, 256, 0, stream>>>(zb, rowptr, colidx, Xball);  // slot 0
    dim3 gb8(256 / 64, NN / 128, 8);
    dim3 ga8(NN / 4, 8, 1);
    // layer 1: shared A (Xball slot 0)
    k_gemm_bf<<<gb8, 256, 0, stream>>>(Xball, Bth, ebh, Heb, nullptr, nullptr, nullptr,
                                       0, (long long)2 * 65536, (long long)NN * 256,
                                       2 * 256, 0);
    // layer 2
    k_agg_b2b<<<ga8, 256, 0, stream>>>(Heb, rowptr, colidx, Xball);
    k_gemm_bf<<<gb8, 256, 0, stream>>>(Xball, Bth + 65536, ebh + 256, Heb,
                                       nullptr, nullptr, nullptr,
                                       (long long)NN * 256, (long long)2 * 65536,
                                       (long long)NN * 256, 2 * 256, 0);
    // layer 3 -> top-2 slot buffers
    k_agg_b2b<<<ga8, 256, 0, stream>>>(Heb, rowptr, colidx, Xball);
    k_gemm_bf<<<gb8, 256, 0, stream>>>(Xball, Bto, ebo, nullptr, Ys, sparse, i1buf,
                                       (long long)NN * 256, (long long)65536,
                                       0, 256, 1);
    k_combine2<<<(NN * 256 / 4) / 256, 256, 0, stream>>>(Ys, out);
}

// Round 5
// 476.278 us; speedup vs baseline: 3.9318x; 1.1238x over previous
//
#include <hip/hip_runtime.h>
#include <math.h>

#define NN 8192      // nodes
#define NE 131072    // edges
#define ZK 288       // padded z width (258 -> 288, multiple of 32)
#define NG 64        // graphs
#define ASPLIT 8     // attention split-K (split = bid&7 -> XCD-pinned)
#define QB 256       // q-rows per attention block (8 waves x 32)
#define KB 32        // keys per attention chunk

typedef __attribute__((ext_vector_type(8))) short bf16x8;
typedef __attribute__((ext_vector_type(4))) float f32x4;
typedef __attribute__((ext_vector_type(8))) _Float16 f16x8;
typedef __attribute__((ext_vector_type(4))) _Float16 f16x4;

static __device__ __forceinline__ unsigned short f2bf(float f) {
    unsigned u = __float_as_uint(f);
    unsigned r = (u + 0x7FFFu + ((u >> 16) & 1u)) >> 16;   // RNE
    return (unsigned short)r;
}
static __device__ __forceinline__ float b2f(unsigned short h) {
    return __uint_as_float(((unsigned)h) << 16);
}

// ------------------------- counts via per-block LDS histograms (G12)
__global__ __launch_bounds__(256) void k_counts(const int* __restrict__ ei,
    const int* __restrict__ batch, int* ncnt, int* ecnt, int* indeg)
{
    __shared__ int he[NG], hn[NG];
    const int t = threadIdx.x, b = blockIdx.x;
    if (t < NG) { he[t] = 0; hn[t] = 0; }
    __syncthreads();
    const int e0 = b * (NE / 64);
#pragma unroll
    for (int i = 0; i < (NE / 64) / 256; ++i) {
        int idx = e0 + i * 256 + t;
        int src = ei[idx], dst = ei[NE + idx];
        atomicAdd(&he[batch[src]], 1);
        atomicAdd(&indeg[dst], 1);
    }
    if (t < 128) atomicAdd(&hn[batch[b * 128 + t]], 1);
    __syncthreads();
    if (t < NG) {
        if (he[t]) atomicAdd(&ecnt[t], he[t]);
        if (hn[t]) atomicAdd(&ncnt[t], hn[t]);
    }
}

// ---------------- encoder + size feats -> z (fp32, ZK) and zb (bf16, 256)
__global__ __launch_bounds__(256) void k_encoder(const float* __restrict__ x,
    const float* __restrict__ encW, const float* __restrict__ encb,
    const int* __restrict__ batch, const int* __restrict__ ncnt,
    const int* __restrict__ ecnt, float* __restrict__ z,
    unsigned short* __restrict__ zb)
{
    int n = blockIdx.x, c = threadIdx.x;
    __shared__ float xr[8];
    if (c < 6) xr[c] = x[n * 6 + c];
    __syncthreads();
    float a = encb[c];
#pragma unroll
    for (int i = 0; i < 6; ++i) a = fmaf(xr[i], encW[i * 256 + c], a);
    float h = fmaxf(a, 0.f);
    z[n * ZK + c] = h;
    zb[n * 256 + c] = f2bf(h);
    if (c == 0) {
        int g = batch[n];
        z[n * ZK + 256] = log1pf((float)ncnt[g]);
        z[n * ZK + 257] = log1pf((float)ecnt[g]);
    }
    if (c >= 2 && c < 32) z[n * ZK + 256 + c] = 0.f;  // zero pad 258..287
}

// ---------------------------------------------------------------- CSR build
__global__ __launch_bounds__(256) void k_scan(const int* __restrict__ indeg,
                                              int* __restrict__ rowptr)
{
    __shared__ int part[256];
    int t = threadIdx.x;
    int base = t * 32, s = 0;
    for (int i = 0; i < 32; ++i) s += indeg[base + i];
    part[t] = s;
    __syncthreads();
    if (t == 0) {
        int run = 0;
        for (int i = 0; i < 256; ++i) { int v = part[i]; part[i] = run; run += v; }
        rowptr[NN] = run;
    }
    __syncthreads();
    int run = part[t];
    for (int i = 0; i < 32; ++i) { rowptr[base + i] = run; run += indeg[base + i]; }
}

__global__ __launch_bounds__(256) void k_fill(const int* __restrict__ ei,
    const int* __restrict__ rowptr, int* __restrict__ cursor, int* __restrict__ colidx)
{
    int tid = blockIdx.x * 256 + threadIdx.x;
    if (tid >= NE) return;
    int dst = ei[NE + tid];
    int pos = atomicAdd(&cursor[dst], 1);
    colidx[rowptr[dst] + pos] = ei[tid];
}

// ------------------------------------------------------- weight preparation
__global__ __launch_bounds__(256) void k_prep_qk(const float* __restrict__ qW,
    const float* __restrict__ kW, float* __restrict__ Wq, float* __restrict__ Wk)
{
    int idx = blockIdx.x * 256 + threadIdx.x;  // < ZK*256 exactly
    int r = idx >> 8, c = idx & 255;
    Wq[idx] = (r < 258) ? qW[r * 256 + c] : 0.f;
    Wk[idx] = (r < 258) ? kW[r * 256 + c] : 0.f;
}

// W_vo = v_W @ out_W (padded to ZK rows), bvo = v_b @ out_W
__global__ __launch_bounds__(256) void k_prep_vo(const float* __restrict__ vW,
    const float* __restrict__ vb, const float* __restrict__ outW,
    float* __restrict__ Wvo, float* __restrict__ bvo)
{
    int idx = blockIdx.x * 256 + threadIdx.x;
    if (idx < ZK * 8) {
        int r = idx >> 3, e = idx & 7;
        float s = 0.f;
        if (r < 258)
            for (int c = 0; c < 256; ++c) s = fmaf(vW[r * 256 + c], outW[c * 8 + e], s);
        Wvo[idx] = s;
    } else if (idx < ZK * 8 + 8) {
        int e = idx - ZK * 8;
        float s = 0.f;
        for (int c = 0; c < 256; ++c) s = fmaf(vb[c], outW[c * 8 + e], s);
        bvo[e] = s;
    }
}

// expert weights -> bf16, transposed to [out][in] so B-frags load contiguous
__global__ __launch_bounds__(256) void k_prep_w(const float* __restrict__ eWh,
    const float* __restrict__ eWo, unsigned short* __restrict__ Bth,
    unsigned short* __restrict__ Bto)
{
    int id = blockIdx.x * 256 + threadIdx.x;
    if (id < 16 * 65536) {
        int h = id & 255, kcol = (id >> 8) & 255, m = id >> 16;  // m = e*2+l
        Bth[id] = f2bf(eWh[((size_t)m * 256 + h) * 256 + kcol]);
    } else if (id < 24 * 65536) {
        int j = id - 16 * 65536;
        int h = j & 255, o = (j >> 8) & 255, e = j >> 16;
        Bto[j] = f2bf(eWo[((size_t)e * 256 + h) * 256 + o]);
    }
}

// ---------------- fp32 GEMM writing split-fp16 (hi,lo); z-batched over q/k
__global__ __launch_bounds__(256) void k_gemm_qk(
    const float* __restrict__ A,
    const float* __restrict__ Wq, const float* __restrict__ Wk,
    const float* __restrict__ qb, const float* __restrict__ kb,
    _Float16* __restrict__ qh, _Float16* __restrict__ ql,
    _Float16* __restrict__ kh, _Float16* __restrict__ kl,
    float scale, int K)
{
    const float* B    = blockIdx.z ? Wk : Wq;
    const float* bias = blockIdx.z ? kb : qb;
    _Float16* Ch = blockIdx.z ? kh : qh;
    _Float16* Cl = blockIdx.z ? kl : ql;
    const float scl = blockIdx.z ? 1.0f : scale;
    __shared__ float As[32][132];
    __shared__ float Bs[32][68];
    int t = threadIdx.x;
    int m0 = blockIdx.y * 128, n0 = blockIdx.x * 64;
    int tr = t & 15, tc = t >> 4;
    float acc[8][4];
#pragma unroll
    for (int i = 0; i < 8; ++i)
#pragma unroll
        for (int j = 0; j < 4; ++j) acc[i][j] = 0.f;

    for (int k0 = 0; k0 < K; k0 += 32) {
#pragma unroll
        for (int i = 0; i < 4; ++i) {
            int f = t + 256 * i;
            int kc = f & 7, row = f >> 3;
            float4 v = *(const float4*)&A[(size_t)(m0 + row) * ZK + k0 + 4 * kc];
            As[4 * kc + 0][row] = v.x; As[4 * kc + 1][row] = v.y;
            As[4 * kc + 2][row] = v.z; As[4 * kc + 3][row] = v.w;
        }
#pragma unroll
        for (int i = 0; i < 2; ++i) {
            int f = t + 256 * i;
            int nc = f & 15, krow = f >> 4;
            *(float4*)&Bs[krow][4 * nc] =
                *(const float4*)&B[(size_t)(k0 + krow) * 256 + n0 + 4 * nc];
        }
        __syncthreads();
#pragma unroll
        for (int kk = 0; kk < 32; ++kk) {
            float4 a0 = *(const float4*)&As[kk][4 * tr];
            float4 a1 = *(const float4*)&As[kk][64 + 4 * tr];
            float4 b  = *(const float4*)&Bs[kk][4 * tc];
            const float av0[4] = {a0.x, a0.y, a0.z, a0.w};
            const float av1[4] = {a1.x, a1.y, a1.z, a1.w};
            const float bv[4]  = {b.x, b.y, b.z, b.w};
#pragma unroll
            for (int i = 0; i < 4; ++i)
#pragma unroll
                for (int j = 0; j < 4; ++j) {
                    acc[i][j]     = fmaf(av0[i], bv[j], acc[i][j]);
                    acc[4 + i][j] = fmaf(av1[i], bv[j], acc[4 + i][j]);
                }
        }
        __syncthreads();
    }
    float4 bi = *(const float4*)&bias[n0 + 4 * tc];
    const float bb[4] = {bi.x, bi.y, bi.z, bi.w};
#pragma unroll
    for (int h = 0; h < 2; ++h)
#pragma unroll
        for (int i = 0; i < 4; ++i) {
            int m = m0 + h * 64 + 4 * tr + i;
            f16x4 vh, vl;
#pragma unroll
            for (int j = 0; j < 4; ++j) {
                float v = (acc[h * 4 + i][j] + bb[j]) * scl;
                _Float16 hi = (_Float16)v;
                vh[j] = hi;
                vl[j] = (_Float16)(v - (float)hi);
            }
            *(f16x4*)&Ch[(size_t)m * 256 + n0 + 4 * tc] = vh;
            *(f16x4*)&Cl[(size_t)m * 256 + n0 + 4 * tc] = vl;
        }
}

// ----------------------------------------------------- bf16 MFMA GEMM
// 1-D grid: expert = bid&7 (XCD-pinned), tile = bid>>3 (4 x-tiles, 64 y-tiles)
// mode 0: relu -> bf16 Cb.  mode 1: Ys[slot] = w*(acc+bias) (top-2 slots).
__global__ __launch_bounds__(256) void k_gemm_bf(
    const unsigned short* __restrict__ A,
    const unsigned short* __restrict__ Bt,
    const float* __restrict__ bias,
    unsigned short* __restrict__ Cb,
    float* __restrict__ Ys,
    const float* __restrict__ sparse,
    const int* __restrict__ i1,
    long long aStrideZ, long long btStrideZ, long long cStrideZ, int biasStrideZ,
    int mode)
{
    const int bid = blockIdx.x;
    const int ez = bid & 7;
    const int tile = bid >> 3;
    const int n0 = (tile & 3) * 64, m0 = (tile >> 2) * 128;
    A    += (size_t)ez * aStrideZ;
    Bt   += (size_t)ez * btStrideZ;
    bias += (size_t)ez * biasStrideZ;
    if (mode == 0) Cb += (size_t)ez * cStrideZ;
    __shared__ unsigned short As[128][40];
    __shared__ unsigned short Bs[64][40];
    const int t = threadIdx.x;
    const int wid = t >> 6, lane = t & 63;
    const int wr = wid >> 1, wc = wid & 1;
    const int lr = lane & 15, lg = lane >> 4;
    f32x4 acc[4][2];
#pragma unroll
    for (int mf = 0; mf < 4; ++mf)
#pragma unroll
        for (int nf = 0; nf < 2; ++nf) acc[mf][nf] = (f32x4){0.f, 0.f, 0.f, 0.f};

    const int rA0 = t >> 2, cA0 = t & 3;
    for (int k0 = 0; k0 < 256; k0 += 32) {
        uint4 va = *(const uint4*)&A[(size_t)(m0 + rA0) * 256 + k0 + 8 * cA0];
        uint4 vb = *(const uint4*)&A[(size_t)(m0 + 64 + rA0) * 256 + k0 + 8 * cA0];
        uint4 vB = *(const uint4*)&Bt[(size_t)(n0 + rA0) * 256 + k0 + 8 * cA0];
        *(uint4*)&As[rA0][8 * cA0] = va;
        *(uint4*)&As[64 + rA0][8 * cA0] = vb;
        *(uint4*)&Bs[rA0][8 * cA0] = vB;
        __syncthreads();
        bf16x8 a[4], b[2];
#pragma unroll
        for (int mf = 0; mf < 4; ++mf)
            a[mf] = *(const bf16x8*)&As[wr * 64 + mf * 16 + lr][8 * lg];
#pragma unroll
        for (int nf = 0; nf < 2; ++nf)
            b[nf] = *(const bf16x8*)&Bs[wc * 32 + nf * 16 + lr][8 * lg];
#pragma unroll
        for (int mf = 0; mf < 4; ++mf)
#pragma unroll
            for (int nf = 0; nf < 2; ++nf)
                acc[mf][nf] = __builtin_amdgcn_mfma_f32_16x16x32_bf16(
                    a[mf], b[nf], acc[mf][nf], 0, 0, 0);
        __syncthreads();
    }
    if (mode == 0) {
#pragma unroll
        for (int mf = 0; mf < 4; ++mf)
#pragma unroll
            for (int reg = 0; reg < 4; ++reg) {
                int m = m0 + wr * 64 + mf * 16 + lg * 4 + reg;
#pragma unroll
                for (int nf = 0; nf < 2; ++nf) {
                    int c = n0 + wc * 32 + nf * 16 + lr;
                    float v = acc[mf][nf][reg] + bias[c];
                    Cb[(size_t)m * 256 + c] = f2bf(fmaxf(v, 0.f));
                }
            }
    } else {
#pragma unroll
        for (int mf = 0; mf < 4; ++mf)
#pragma unroll
            for (int reg = 0; reg < 4; ++reg) {
                int m = m0 + wr * 64 + mf * 16 + lg * 4 + reg;
                float w = sparse[m * 8 + ez];
                if (w != 0.f) {
                    int slot = (ez == i1[m]) ? 0 : 1;
                    float* dst = Ys + (size_t)slot * NN * 256 + (size_t)m * 256;
#pragma unroll
                    for (int nf = 0; nf < 2; ++nf) {
                        int c = n0 + wc * 32 + nf * 16 + lr;
                        dst[c] = w * (acc[mf][nf][reg] + bias[c]);
                    }
                }
            }
    }
}

// ------------------------------------------------------------- vo = z @ Wvo
__global__ __launch_bounds__(256) void k_vo(const float* __restrict__ z,
    const float* __restrict__ Wvo, const float* __restrict__ bvo,
    float* __restrict__ vo)
{
    int n = blockIdx.x * 4 + (threadIdx.x >> 6);
    int lane = threadIdx.x & 63;
    float p[8];
#pragma unroll
    for (int e = 0; e < 8; ++e) p[e] = 0.f;
    for (int kk = lane; kk < ZK; kk += 64) {
        float zv = z[(size_t)n * ZK + kk];
        float4 w0 = *(const float4*)&Wvo[kk * 8];
        float4 w1 = *(const float4*)&Wvo[kk * 8 + 4];
        p[0] = fmaf(zv, w0.x, p[0]); p[1] = fmaf(zv, w0.y, p[1]);
        p[2] = fmaf(zv, w0.z, p[2]); p[3] = fmaf(zv, w0.w, p[3]);
        p[4] = fmaf(zv, w1.x, p[4]); p[5] = fmaf(zv, w1.y, p[5]);
        p[6] = fmaf(zv, w1.z, p[6]); p[7] = fmaf(zv, w1.w, p[7]);
    }
#pragma unroll
    for (int msk = 1; msk <= 32; msk <<= 1)
#pragma unroll
        for (int e = 0; e < 8; ++e) p[e] += __shfl_xor(p[e], msk);
    if (lane == 0) {
#pragma unroll
        for (int e = 0; e < 8; ++e) vo[n * 8 + e] = p[e] + bvo[e];
    }
}

// ------------------- split-fp16 MFMA flash attention, swapped operands
// A = K from LDS (shared across 2 row-sets), B = Q in regs (32 rows/wave).
// 8 waves x 32 rows = QB 256; split = bid&7 (XCD-pinned K-slice of 1024 keys).
// s = kh*qh + kl*qh + kh*ql. C layout: col=lane&15 = q-row -> per-lane
// private online softmax (keys kt*16+4g+reg); merge = 2 butterfly steps.
__global__ __launch_bounds__(512, 2) void k_attn_mfma(
    const _Float16* __restrict__ qh_, const _Float16* __restrict__ ql_,
    const _Float16* __restrict__ kh, const _Float16* __restrict__ kl,
    const float* __restrict__ vo, float* __restrict__ pm,
    float* __restrict__ pl, float* __restrict__ pacc)
{
    __shared__ char lds[2][KB * 1024];   // per key: 512B hi | 512B lo, swizzled
    const int bid = blockIdx.x;
    const int split = bid & 7;
    const int rowblk = bid >> 3;
    const int n0 = rowblk * QB;
    const int t = threadIdx.x, w = t >> 6, lane = t & 63;
    const int g = lane >> 4, c = lane & 15;

    // Q B-fragments (col=lane&15=row, k=8*g + st*32), persistent in registers
    f16x8 bqh[2][8], bql[2][8];
#pragma unroll
    for (int rs = 0; rs < 2; ++rs) {
        const int row = n0 + w * 32 + rs * 16 + c;
#pragma unroll
        for (int st = 0; st < 8; ++st) {
            bqh[rs][st] = *(const f16x8*)&qh_[(size_t)row * 256 + st * 32 + g * 8];
            bql[rs][st] = *(const f16x8*)&ql_[(size_t)row * 256 + st * 32 + g * 8];
        }
    }
    float m_[2] = {-INFINITY, -INFINITY};
    float l_[2] = {0.f, 0.f};
    float pv[2][8];
#pragma unroll
    for (int rs = 0; rs < 2; ++rs)
#pragma unroll
        for (int e = 0; e < 8; ++e) pv[rs][e] = 0.f;

    const int kbase0 = split * 1024;
    // stage: 32 keys x (512B hi | 512B lo); 16B-slot XOR swizzle by key&7
    auto stage = [&](char* buf, int kb) {
#pragma unroll
        for (int i = 0; i < 4; ++i) {
            int u = i * 512 + t;
            int key = u >> 6, ur = u & 63;
            int half = ur >> 5, c16 = ur & 31;
            const _Float16* src = half ? kl : kh;
            uint4 v = *(const uint4*)&src[(size_t)(kb + key) * 256 + c16 * 8];
            int dst = key * 1024 + half * 512 + ((c16 * 16) ^ ((key & 7) << 4));
            *(uint4*)&buf[dst] = v;
        }
    };
    stage(lds[0], kbase0);
    __syncthreads();
    int cur = 0;
    for (int ch = 0; ch < 32; ++ch) {
        const int kbase = kbase0 + ch * KB;
        if (ch + 1 < 32) stage(lds[cur ^ 1], kbase + KB);
#pragma unroll
        for (int kt = 0; kt < 2; ++kt) {
            const char* kbp = &lds[cur][(kt * 16 + c) * 1024];
            const int swz = ((kt * 16 + c) & 7) << 4;
            f32x4 acc0 = (f32x4){0.f, 0.f, 0.f, 0.f};
            f32x4 acc1 = (f32x4){0.f, 0.f, 0.f, 0.f};
#pragma unroll
            for (int st = 0; st < 8; ++st) {
                const int off = (st * 64 + g * 16) ^ swz;
                f16x8 kah = *(const f16x8*)(kbp + off);
                f16x8 kal = *(const f16x8*)(kbp + 512 + off);
                acc0 = __builtin_amdgcn_mfma_f32_16x16x32_f16(kah, bqh[0][st], acc0, 0, 0, 0);
                acc0 = __builtin_amdgcn_mfma_f32_16x16x32_f16(kal, bqh[0][st], acc0, 0, 0, 0);
                acc0 = __builtin_amdgcn_mfma_f32_16x16x32_f16(kah, bql[0][st], acc0, 0, 0, 0);
                acc1 = __builtin_amdgcn_mfma_f32_16x16x32_f16(kah, bqh[1][st], acc1, 0, 0, 0);
                acc1 = __builtin_amdgcn_mfma_f32_16x16x32_f16(kal, bqh[1][st], acc1, 0, 0, 0);
                acc1 = __builtin_amdgcn_mfma_f32_16x16x32_f16(kah, bql[1][st], acc1, 0, 0, 0);
            }
            // lane's keys this tile: kb2 .. kb2+3
            const int kb2 = kbase + kt * 16 + 4 * g;
            float4 w0[4], w1[4];
#pragma unroll
            for (int r = 0; r < 4; ++r) {
                w0[r] = *(const float4*)&vo[(kb2 + r) * 8];
                w1[r] = *(const float4*)&vo[(kb2 + r) * 8 + 4];
            }
#pragma unroll
            for (int rs = 0; rs < 2; ++rs) {
                f32x4 s = rs ? acc1 : acc0;
                float cm = fmaxf(fmaxf(s[0], s[1]), fmaxf(s[2], s[3]));
                float mn = fmaxf(m_[rs], cm);
                float rsc = __expf(m_[rs] - mn);
                float p0 = __expf(s[0] - mn);
                float p1 = __expf(s[1] - mn);
                float p2 = __expf(s[2] - mn);
                float p3 = __expf(s[3] - mn);
                l_[rs] = l_[rs] * rsc + (p0 + p1 + p2 + p3);
                m_[rs] = mn;
                pv[rs][0] = pv[rs][0]*rsc + p0*w0[0].x + p1*w0[1].x + p2*w0[2].x + p3*w0[3].x;
                pv[rs][1] = pv[rs][1]*rsc + p0*w0[0].y + p1*w0[1].y + p2*w0[2].y + p3*w0[3].y;
                pv[rs][2] = pv[rs][2]*rsc + p0*w0[0].z + p1*w0[1].z + p2*w0[2].z + p3*w0[3].z;
                pv[rs][3] = pv[rs][3]*rsc + p0*w0[0].w + p1*w0[1].w + p2*w0[2].w + p3*w0[3].w;
                pv[rs][4] = pv[rs][4]*rsc + p0*w1[0].x + p1*w1[1].x + p2*w1[2].x + p3*w1[3].x;
                pv[rs][5] = pv[rs][5]*rsc + p0*w1[0].y + p1*w1[1].y + p2*w1[2].y + p3*w1[3].y;
                pv[rs][6] = pv[rs][6]*rsc + p0*w1[0].z + p1*w1[1].z + p2*w1[2].z + p3*w1[3].z;
                pv[rs][7] = pv[rs][7]*rsc + p0*w1[0].w + p1*w1[1].w + p2*w1[2].w + p3*w1[3].w;
            }
        }
        __syncthreads();
        cur ^= 1;
    }
    // --- merge across the 4 lanes (g=0..3) sharing each q-row ---
#pragma unroll
    for (int msk = 16; msk <= 32; msk <<= 1) {
#pragma unroll
        for (int rs = 0; rs < 2; ++rs) {
            float mo = __shfl_xor(m_[rs], msk);
            float lo = __shfl_xor(l_[rs], msk);
            float mn = fmaxf(m_[rs], mo);
            float a = __expf(m_[rs] - mn), b = __expf(mo - mn);
            l_[rs] = l_[rs] * a + lo * b;
#pragma unroll
            for (int e = 0; e < 8; ++e) {
                float po = __shfl_xor(pv[rs][e], msk);
                pv[rs][e] = pv[rs][e] * a + po * b;
            }
            m_[rs] = mn;
        }
    }
    if (g == 0) {
#pragma unroll
        for (int rs = 0; rs < 2; ++rs) {
            int n = n0 + w * 32 + rs * 16 + c;
            pm[split * NN + n] = m_[rs];
            pl[split * NN + n] = l_[rs];
#pragma unroll
            for (int e = 0; e < 8; ++e)
                pacc[(size_t)split * NN * 8 + n * 8 + e] = pv[rs][e];
        }
    }
}

// ----------------------------------- merge split-K partials -> top2 weights
__global__ __launch_bounds__(256) void k_attn_merge(
    const float* __restrict__ pm, const float* __restrict__ pl,
    const float* __restrict__ pacc, const float* __restrict__ outb,
    float* __restrict__ sparse, int* __restrict__ i1o)
{
    int n = blockIdx.x * 256 + threadIdx.x;
    float mn = -INFINITY;
#pragma unroll
    for (int s = 0; s < ASPLIT; ++s) mn = fmaxf(mn, pm[s * NN + n]);
    float l = 0.f;
    float lg[8];
#pragma unroll
    for (int e = 0; e < 8; ++e) lg[e] = 0.f;
#pragma unroll
    for (int s = 0; s < ASPLIT; ++s) {
        float r = __expf(pm[s * NN + n] - mn);
        l += pl[s * NN + n] * r;
#pragma unroll
        for (int e = 0; e < 8; ++e)
            lg[e] += pacc[(size_t)s * NN * 8 + n * 8 + e] * r;
    }
    float inv = 1.f / l;
#pragma unroll
    for (int e = 0; e < 8; ++e) lg[e] = lg[e] * inv + outb[e];
    int i1 = 0; float v1 = lg[0];
#pragma unroll
    for (int e = 1; e < 8; ++e) if (lg[e] > v1) { v1 = lg[e]; i1 = e; }
    int i2 = -1; float v2 = -INFINITY;
#pragma unroll
    for (int e = 0; e < 8; ++e) if (e != i1 && lg[e] > v2) { v2 = lg[e]; i2 = e; }
    float e2 = __expf(v2 - v1);
    float w1 = 1.f / (1.f + e2);
    float w2 = e2 / (1.f + e2);
#pragma unroll
    for (int e = 0; e < 8; ++e)
        sparse[n * 8 + e] = (e == i1) ? w1 : ((e == i2) ? w2 : 0.f);
    i1o[n] = i1;
}

// ------------------- bf16 gather-mean: X = bf16(src + neigh_mean(src))
// 1-D grid: expert = bid & ((1<<eshift)-1)  (XCD-pinned), node-blk = bid>>eshift
__global__ __launch_bounds__(256) void k_agg_b2b(
    const unsigned short* __restrict__ HeAll, const int* __restrict__ rowptr,
    const int* __restrict__ colidx, unsigned short* __restrict__ XAll,
    int eshift)
{
    const int bid = blockIdx.x;
    const int e = bid & ((1 << eshift) - 1);
    const int nb = bid >> eshift;
    const unsigned short* He = HeAll + (size_t)e * NN * 256;
    unsigned short* X = XAll + (size_t)e * NN * 256;
    int n = nb * 4 + (threadIdx.x >> 6);
    int c4 = (threadIdx.x & 63) * 4;
    int r0 = rowptr[n], r1 = rowptr[n + 1];
    float a0 = 0.f, a1 = 0.f, a2 = 0.f, a3 = 0.f;
    for (int i = r0; i < r1; ++i) {
        int sn = colidx[i];
        ushort4 v = *(const ushort4*)&He[(size_t)sn * 256 + c4];
        a0 += b2f(v.x); a1 += b2f(v.y); a2 += b2f(v.z); a3 += b2f(v.w);
    }
    int deg = r1 - r0;
    float inv = 1.f / (float)(deg > 1 ? deg : 1);
    ushort4 self = *(const ushort4*)&He[(size_t)n * 256 + c4];
    ushort4 o;
    o.x = f2bf(b2f(self.x) + a0 * inv); o.y = f2bf(b2f(self.y) + a1 * inv);
    o.z = f2bf(b2f(self.z) + a2 * inv); o.w = f2bf(b2f(self.w) + a3 * inv);
    *(ushort4*)&X[(size_t)n * 256 + c4] = o;
}

// ------------------------------------------------ out = Ys[0] + Ys[1]
__global__ __launch_bounds__(256) void k_combine2(const float* __restrict__ Ys,
                                                  float* __restrict__ out)
{
    int i = (blockIdx.x * 256 + threadIdx.x) * 4;
    float4 a = *(const float4*)&Ys[i];
    float4 b = *(const float4*)&Ys[(size_t)NN * 256 + i];
    float4 o;
    o.x = a.x + b.x; o.y = a.y + b.y; o.z = a.z + b.z; o.w = a.w + b.w;
    *(float4*)&out[i] = o;
}

// ==========================================================================
extern "C" void kernel_launch(void* const* d_in, const int* in_sizes, int n_in,
                              void* d_out, int out_size, void* d_ws, size_t ws_size,
                              hipStream_t stream)
{
    (void)n_in; (void)out_size;
    const float* x     = (const float*)d_in[0];
    const int*   ei    = (const int*)d_in[1];
    const int*   batch = (const int*)d_in[2];
    const float* encW  = (const float*)d_in[3];
    const float* encb  = (const float*)d_in[4];
    const float* qW    = (const float*)d_in[5];
    const float* qb    = (const float*)d_in[6];
    const float* kW    = (const float*)d_in[7];
    const float* kb    = (const float*)d_in[8];
    const float* vW    = (const float*)d_in[9];
    const float* vb    = (const float*)d_in[10];
    const float* outW  = (const float*)d_in[11];
    const float* outb  = (const float*)d_in[12];
    const float* eWh   = (const float*)d_in[13];
    const float* ebh   = (const float*)d_in[14];
    const float* eWo   = (const float*)d_in[15];
    const float* ebo   = (const float*)d_in[16];
    float* out = (float*)d_out;
    if (in_sizes[0] != NN * 6 || in_sizes[1] != 2 * NE) return;

    char* wsp = (char*)d_ws;
    size_t off = 0;
    auto alloc = [&](size_t bytes) -> void* {
        void* p = wsp + off;
        off += (bytes + 511) & ~(size_t)511;
        return p;
    };
    float* z   = (float*)alloc((size_t)NN * ZK * 4);
    unsigned short* zb = (unsigned short*)alloc((size_t)NN * 256 * 2);
    // 16MB block: q/k split-fp16; reused as Ys (2 x NN x 256 fp32) after attn
    _Float16* qh = (_Float16*)alloc((size_t)4 * NN * 256 * 2);
    _Float16* ql = qh + (size_t)NN * 256;
    _Float16* kh = ql + (size_t)NN * 256;
    _Float16* kl = kh + (size_t)NN * 256;
    float* Ys = (float*)qh;
    float* vo     = (float*)alloc((size_t)NN * 8 * 4);
    float* sparse = (float*)alloc((size_t)NN * 8 * 4);
    int*   i1buf  = (int*)alloc((size_t)NN * 4);
    unsigned short* Xball = (unsigned short*)alloc((size_t)8 * NN * 256 * 2);
    unsigned short* Heb   = (unsigned short*)alloc((size_t)8 * NN * 256 * 2);
    unsigned short* Bth   = (unsigned short*)alloc((size_t)16 * 65536 * 2);
    unsigned short* Bto   = (unsigned short*)alloc((size_t)8 * 65536 * 2);
    float* Wq   = (float*)alloc((size_t)ZK * 256 * 4);
    float* Wk   = (float*)alloc((size_t)ZK * 256 * 4);
    float* Wvo  = (float*)alloc((size_t)ZK * 8 * 4);
    float* bvo  = (float*)alloc(8 * 4);
    float* pm   = (float*)alloc((size_t)ASPLIT * NN * 4);
    float* plb  = (float*)alloc((size_t)ASPLIT * NN * 4);
    float* pacc = (float*)alloc((size_t)ASPLIT * NN * 8 * 4);
    int* ints   = (int*)alloc((size_t)(NG + NG + NN + NN) * 4);
    int* ncnt = ints, *ecnt = ints + NG, *indeg = ecnt + NG, *cursor = indeg + NN;
    int* rowptr = (int*)alloc((size_t)(NN + 1) * 4);
    int* colidx = (int*)alloc((size_t)NE * 4);
    if (off > ws_size) return;

    hipMemsetAsync(ints, 0, (size_t)(NG + NG + NN + NN) * 4, stream);
    k_counts<<<64, 256, 0, stream>>>(ei, batch, ncnt, ecnt, indeg);
    k_prep_qk<<<ZK, 256, 0, stream>>>(qW, kW, Wq, Wk);
    k_prep_vo<<<(ZK * 8 + 8 + 255) / 256, 256, 0, stream>>>(vW, vb, outW, Wvo, bvo);
    k_prep_w<<<(24 * 65536) / 256, 256, 0, stream>>>(eWh, eWo, Bth, Bto);
    k_encoder<<<NN, 256, 0, stream>>>(x, encW, encb, batch, ncnt, ecnt, z, zb);
    k_scan<<<1, 256, 0, stream>>>(indeg, rowptr);
    k_fill<<<(NE + 255) / 256, 256, 0, stream>>>(ei, rowptr, cursor, colidx);

    float scale = 1.f / sqrtf(258.f);
    dim3 gqk(256 / 64, NN / 128, 2);
    k_gemm_qk<<<gqk, 256, 0, stream>>>(z, Wq, Wk, qb, kb, qh, ql, kh, kl, scale, ZK);
    k_vo<<<NN / 4, 256, 0, stream>>>(z, Wvo, bvo, vo);

    k_attn_mfma<<<(NN / QB) * ASPLIT, 512, 0, stream>>>(qh, ql, kh, kl, vo, pm, plb, pacc);
    k_attn_merge<<<NN / 256, 256, 0, stream>>>(pm, plb, pacc, outb, sparse, i1buf);

    // ---- experts: 3 batched agg + 3 batched MFMA GEMMs + combine ----
    k_agg_b2b<<<NN / 4, 256, 0, stream>>>(zb, rowptr, colidx, Xball, 0);  // slot 0
    // layer 1: shared A (Xball slot 0)
    k_gemm_bf<<<2048, 256, 0, stream>>>(Xball, Bth, ebh, Heb, nullptr, nullptr, nullptr,
                                        0, (long long)2 * 65536, (long long)NN * 256,
                                        2 * 256, 0);
    // layer 2
    k_agg_b2b<<<(NN / 4) * 8, 256, 0, stream>>>(Heb, rowptr, colidx, Xball, 3);
    k_gemm_bf<<<2048, 256, 0, stream>>>(Xball, Bth + 65536, ebh + 256, Heb,
                                        nullptr, nullptr, nullptr,
                                        (long long)NN * 256, (long long)2 * 65536,
                                        (long long)NN * 256, 2 * 256, 0);
    // layer 3 -> top-2 slot buffers
    k_agg_b2b<<<(NN / 4) * 8, 256, 0, stream>>>(Heb, rowptr, colidx, Xball, 3);
    k_gemm_bf<<<2048, 256, 0, stream>>>(Xball, Bto, ebo, nullptr, Ys, sparse, i1buf,
                                        (long long)NN * 256, (long long)65536,
                                        0, 256, 1);
    k_combine2<<<(NN * 256 / 4) / 256, 256, 0, stream>>>(Ys, out);
}